// Round 6
// baseline (217.858 us; speedup 1.0000x reference)
//
#include <hip/hip_runtime.h>

#define BB 4
#define NN 32768
#define KKN 16          // neighbors per node
#define IN_DIM 32
#define HID 64
#define OUT_DIM 32
#define KH 64
#define WS 88           // LDS row stride in f16 elems (176 B, 16B-aligned)
#define TOT (BB * NN)   // 131072 = 2^17
#define NWAVES 4096     // grid 1024 blocks x 4 waves (4 blocks/CU co-resident)

typedef _Float16 f16;
typedef f16 f16x2 __attribute__((ext_vector_type(2)));
typedef f16 f16x4 __attribute__((ext_vector_type(4)));
typedef f16 f16x8 __attribute__((ext_vector_type(8)));
typedef float f32x4 __attribute__((ext_vector_type(4)));
typedef __fp16 hf16x2 __attribute__((ext_vector_type(2)));   // builtin's native type
typedef unsigned int u32x4 __attribute__((ext_vector_type(4)));

#define H2(c) ((f16x2){(f16)(c), (f16)(c)})

// packed f32->f16x2 convert (v_cvt_pkrtz_f16_f32), bit-cast to _Float16 vec
__device__ __forceinline__ f16x2 cvt2(float a, float b) {
    hf16x2 r = __builtin_amdgcn_cvt_pkrtz(a, b);
    return __builtin_bit_cast(f16x2, r);
}

// Packed-fp16 polynomial gelu on pre-packed x, no transcendentals, no LDS.
// out = x * (0.5 + s*g(t)), s = clamp(x,±3.5), t = (s/4)^2.
__device__ __forceinline__ f16x2 gelu2h(f16x2 x) {
    f16x2 s  = __builtin_elementwise_min(
                   __builtin_elementwise_max(x, H2(-3.5f)), H2(3.5f));
    f16x2 s4 = s * H2(0.25f);
    f16x2 t  = s4 * s4;                       // in [0, 0.765625]
    f16x2 g  = H2(-1.0110344f);
    g = g * t + H2( 2.85016064f);
    g = g * t + H2(-3.40439040f);
    g = g * t + H2( 2.32402432f);
    g = g * t + H2(-1.04974080f);
    g = g * t + H2( 0.39879504f);
    f16x2 h  = s * g + H2(0.5f);              // Phi(s)
    return x * h;
}
__device__ __forceinline__ f16x2 gelu2(float a, float b) {
    return gelu2h(cvt2(a, b));
}
// bias (packed f16) added AFTER the f32->f16 pack
__device__ __forceinline__ f16x2 gelu2b(float a, float b, f16x2 bias) {
    return gelu2h(cvt2(a, b) + bias);
}

// DPP add: v += lane-permuted v (within 16-lane row).
template <int CTRL>
__device__ __forceinline__ float dppadd(float v) {
    union { float f; int i; } u, r;
    u.f = v;
    r.i = __builtin_amdgcn_update_dpp(0, u.i, CTRL, 0xf, 0xf, true);
    return v + r.f;
}
__device__ __forceinline__ float rowsum16(float v) {
    v = dppadd<0xB1>(v);    // quad xor 1
    v = dppadd<0x4E>(v);    // quad xor 2
    v = dppadd<0x124>(v);   // row rotate 4
    v = dppadd<0x128>(v);   // row rotate 8
    return v;
}

// ---------------- Kernel A: point MLP via MFMA (persistent) ----------------
__global__ __launch_bounds__(256) void point_mlp_kernel(
    const float* __restrict__ inp, const float* __restrict__ Wp1,
    const float* __restrict__ bp1, const float* __restrict__ Wp2,
    const float* __restrict__ bp2, f16* __restrict__ xhf)
{
    __shared__ __align__(16) f16 hb[4][16 * WS];
    const int tid = threadIdx.x, w = tid >> 6, lane = tid & 63;
    const int q = lane >> 4, nl = lane & 15;

    f16x8 w1f[4];
    #pragma unroll
    for (int nb = 0; nb < 4; nb++)
        #pragma unroll
        for (int j = 0; j < 8; j++)
            w1f[nb][j] = (f16)Wp1[(q * 8 + j) * HID + nb * 16 + nl];
    f16x8 w2f[2][2];        // rows pre-permuted by p_inv(k) = (k&3)*16 + k/4
    #pragma unroll
    for (int nb = 0; nb < 2; nb++)
        #pragma unroll
        for (int c = 0; c < 2; c++)
            #pragma unroll
            for (int j = 0; j < 8; j++) {
                int k = c * 32 + q * 8 + j, kp = ((k & 3) << 4) | (k >> 2);
                w2f[nb][c][j] = (f16)Wp2[kp * OUT_DIM + nb * 16 + nl];
            }
    float b1v[4], b2v[2];
    #pragma unroll
    for (int nb = 0; nb < 4; nb++) b1v[nb] = bp1[nb * 16 + nl];
    b2v[0] = bp2[nl]; b2v[1] = bp2[16 + nl];

    const int gw = blockIdx.x * 4 + w;
    const int nw = gridDim.x * 4;

    for (int t = gw; t < TOT / 16; t += nw) {
        const int R = t * 16;
        const float* ap = inp + (size_t)(R + nl) * IN_DIM + q * 8;
        float4 av0 = *(const float4*)ap, av1 = *(const float4*)(ap + 4);
        f16x2 p01 = cvt2(av0.x, av0.y);
        f16x2 p23 = cvt2(av0.z, av0.w);
        f16x2 p45 = cvt2(av1.x, av1.y);
        f16x2 p67 = cvt2(av1.z, av1.w);
        f16x8 af = (f16x8){p01.x, p01.y, p23.x, p23.y, p45.x, p45.y, p67.x, p67.y};

        f32x4 acc[4];
        #pragma unroll
        for (int nb = 0; nb < 4; nb++)
            acc[nb] = (f32x4){b1v[nb], b1v[nb], b1v[nb], b1v[nb]};
        #pragma unroll
        for (int nb = 0; nb < 4; nb++)
            acc[nb] = __builtin_amdgcn_mfma_f32_16x16x32_f16(af, w1f[nb], acc[nb], 0, 0, 0);

        #pragma unroll
        for (int r = 0; r < 4; r++) {
            f16x2 h01 = gelu2(acc[0][r], acc[1][r]);
            f16x2 h23 = gelu2(acc[2][r], acc[3][r]);
            *(f16x4*)&hb[w][(q * 4 + r) * WS + nl * 4] = (f16x4){h01.x, h01.y, h23.x, h23.y};
        }
        f16x8 a0 = *(const f16x8*)&hb[w][nl * WS + q * 8];
        f16x8 a1 = *(const f16x8*)&hb[w][nl * WS + 32 + q * 8];
        f32x4 a2[2];
        #pragma unroll
        for (int nb = 0; nb < 2; nb++) {
            a2[nb] = (f32x4){b2v[nb], b2v[nb], b2v[nb], b2v[nb]};
            a2[nb] = __builtin_amdgcn_mfma_f32_16x16x32_f16(a0, w2f[nb][0], a2[nb], 0, 0, 0);
            a2[nb] = __builtin_amdgcn_mfma_f32_16x16x32_f16(a1, w2f[nb][1], a2[nb], 0, 0, 0);
        }
        #pragma unroll
        for (int r = 0; r < 4; r++)
            #pragma unroll
            for (int nb = 0; nb < 2; nb++)
                xhf[(size_t)(R + q * 4 + r) * OUT_DIM + nb * 16 + nl] = (f16)a2[nb][r];
    }
}

// ---------------- Kernel B: edge MLP, 2 nodes/iter ----------------
// KEY: gather lanes are assigned in MFMA A-frag order — lane (q,nl) loads
// neighbor nbi[node*16+nl]'s bytes q*16..q*16+15 — so the prefetched gather
// register IS the L1 A-operand. No LDS commit, no L1 tile read, no zero-init.
// (A gather's coalescing depends only on the wave's address SET, which is
// invariant under lane permutation.) LDS is used only for the L1->L2 and
// L2->L3 activation transposes.
__global__ __launch_bounds__(256) void gnn_edge_kernel(
    const f16*   __restrict__ xhf,
    const float* __restrict__ igrid, const float* __restrict__ ogrid,
    const int*   __restrict__ nbi,
    const float* __restrict__ Wk1, const float* __restrict__ bk1,
    const float* __restrict__ Wk2, const float* __restrict__ bk2,
    const float* __restrict__ Wk3, const float* __restrict__ bk3,
    const float* __restrict__ gma, const float* __restrict__ bta,
    float* __restrict__ out)
{
    __shared__ __align__(16) f16 tile[8][16 * WS];   // 2 h-tiles per wave (22.5 KB)

    const int tid = threadIdx.x, w = tid >> 6, lane = tid & 63;
    const int q = lane >> 4, nl = lane & 15;
    f16* __restrict__ TA = tile[w * 2];
    f16* __restrict__ TB = tile[w * 2 + 1];

    // ---- weight B-frags in registers ----
    f16x8 w1f[4][2], w2f[4][2], w3f[2][2];
    #pragma unroll
    for (int nb = 0; nb < 4; nb++) {
        #pragma unroll
        for (int j = 0; j < 8; j++) {
            w1f[nb][0][j] = (f16)Wk1[(4 + q * 8 + j) * KH + nb * 16 + nl];
            float v1 = 0.0f;
            if (j < 4 && q == 0) v1 = Wk1[j * KH + nb * 16 + nl];
            w1f[nb][1][j] = (f16)v1;
        }
        #pragma unroll
        for (int c = 0; c < 2; c++)
            #pragma unroll
            for (int j = 0; j < 8; j++) {
                int k = c * 32 + q * 8 + j, kp = ((k & 3) << 4) | (k >> 2);
                w2f[nb][c][j] = (f16)Wk2[kp * KH + nb * 16 + nl];
            }
    }
    // w3 pre-scaled by 1/16: folds the edge-mean into the matmul
    #pragma unroll
    for (int nb = 0; nb < 2; nb++)
        #pragma unroll
        for (int c = 0; c < 2; c++)
            #pragma unroll
            for (int j = 0; j < 8; j++) {
                int k = c * 32 + q * 8 + j, kp = ((k & 3) << 4) | (k >> 2);
                w3f[nb][c][j] = (f16)(Wk3[kp * OUT_DIM + nb * 16 + nl] * 0.0625f);
            }

    // packed-f16 bias pairs for gelu re-injection (per-lane nl only)
    const f16x2 b1p0 = cvt2(bk1[nl],      bk1[16 + nl]);
    const f16x2 b1p1 = cvt2(bk1[32 + nl], bk1[48 + nl]);
    const f16x2 b2p0 = cvt2(bk2[nl],      bk2[16 + nl]);
    const f16x2 b2p1 = cvt2(bk2[32 + nl], bk2[48 + nl]);
    float b3v[2];
    b3v[0] = bk3[nl]; b3v[1] = bk3[16 + nl];
    const float g0 = gma[nl], g1 = gma[16 + nl], be0 = bta[nl], be1 = bta[16 + nl];

    // shared zero C-operand
    const f32x4 zq = (f32x4){0.f, 0.f, 0.f, 0.f};

    const int gw = blockIdx.x * 4 + w;

    // ---- prologue prefetch (pair 0) ----
    // lane (q,nl): neighbor row = nbi[node*16 + nl], bytes q*16..q*16+15
    int tA = gw, tB = gw + NWAVES;
    int nA = nbi[(tA & (NN - 1)) * KKN + nl];
    int nB = nbi[(tB & (NN - 1)) * KKN + nl];
    uint4 fyA = ((const uint4*)(xhf + ((size_t)((tA >> 15) * NN + nA)) * OUT_DIM))[q];
    uint4 fyB = ((const uint4*)(xhf + ((size_t)((tB >> 15) * NN + nB)) * OUT_DIM))[q];
    uint2 paA, paB;                       // packed pos feats [ip.x ip.y | op.x op.y]
    if (q == 0) {
        float2 ip, op;
        ip = ((const float2*)igrid)[nA]; op = ((const float2*)ogrid)[tA & (NN - 1)];
        paA.x = __builtin_bit_cast(unsigned, cvt2(ip.x, ip.y));
        paA.y = __builtin_bit_cast(unsigned, cvt2(op.x, op.y));
        ip = ((const float2*)igrid)[nB]; op = ((const float2*)ogrid)[tB & (NN - 1)];
        paB.x = __builtin_bit_cast(unsigned, cvt2(ip.x, ip.y));
        paB.y = __builtin_bit_cast(unsigned, cvt2(op.x, op.y));
    }
    f16 xA0 = xhf[(size_t)tA * OUT_DIM + nl],      xA1 = xhf[(size_t)tA * OUT_DIM + 16 + nl];
    f16 xB0 = xhf[(size_t)tB * OUT_DIM + nl],      xB1 = xhf[(size_t)tB * OUT_DIM + 16 + nl];

    #pragma unroll 1
    for (int it = 0; it < TOT / (2 * NWAVES); ++it) {
        const float rA0 = (float)xA0, rA1 = (float)xA1, rB0 = (float)xB0, rB1 = (float)xB1;

        // ---- next pair indices (wraparound, always valid) ----
        const int tA2 = (tA + 2 * NWAVES) & (TOT - 1);
        const int tB2 = tA2 + NWAVES;
        const int nA2 = nbi[(tA2 & (NN - 1)) * KKN + nl];
        const int nB2 = nbi[(tB2 & (NN - 1)) * KKN + nl];

        // ---- layer 1: A-operands straight from prefetched registers ----
        f16x8 aA0 = __builtin_bit_cast(f16x8, fyA);
        f16x8 aB0 = __builtin_bit_cast(f16x8, fyB);
        u32x4 uA1 = (u32x4){q == 0 ? paA.x : 0u, q == 0 ? paA.y : 0u, 0u, 0u};
        u32x4 uB1 = (u32x4){q == 0 ? paB.x : 0u, q == 0 ? paB.y : 0u, 0u, 0u};
        f16x8 aA1 = __builtin_bit_cast(f16x8, uA1);
        f16x8 aB1 = __builtin_bit_cast(f16x8, uB1);

        f32x4 cA[4], cB[4];
        #pragma unroll
        for (int nb = 0; nb < 4; nb++) {
            cA[nb] = __builtin_amdgcn_mfma_f32_16x16x32_f16(aA0, w1f[nb][0], zq, 0, 0, 0);
            cB[nb] = __builtin_amdgcn_mfma_f32_16x16x32_f16(aB0, w1f[nb][0], zq, 0, 0, 0);
            cA[nb] = __builtin_amdgcn_mfma_f32_16x16x32_f16(aA1, w1f[nb][1], cA[nb], 0, 0, 0);
            cB[nb] = __builtin_amdgcn_mfma_f32_16x16x32_f16(aB1, w1f[nb][1], cB[nb], 0, 0, 0);
        }
        #pragma unroll
        for (int r = 0; r < 4; r++) {
            f16x2 hA01 = gelu2b(cA[0][r], cA[1][r], b1p0);
            f16x2 hA23 = gelu2b(cA[2][r], cA[3][r], b1p1);
            f16x2 hB01 = gelu2b(cB[0][r], cB[1][r], b1p0);
            f16x2 hB23 = gelu2b(cB[2][r], cB[3][r], b1p1);
            *(f16x4*)&TA[(q * 4 + r) * WS + nl * 4] = (f16x4){hA01.x, hA01.y, hA23.x, hA23.y};
            *(f16x4*)&TB[(q * 4 + r) * WS + nl * 4] = (f16x4){hB01.x, hB01.y, hB23.x, hB23.y};
        }

        // ---- issue next pair's gathers (overlap layers 2-3) ----
        uint4 fyA2 = ((const uint4*)(xhf + ((size_t)((tA2 >> 15) * NN + nA2)) * OUT_DIM))[q];
        uint4 fyB2 = ((const uint4*)(xhf + ((size_t)((tB2 >> 15) * NN + nB2)) * OUT_DIM))[q];
        uint2 paA2, paB2;
        if (q == 0) {
            float2 ip, op;
            ip = ((const float2*)igrid)[nA2]; op = ((const float2*)ogrid)[tA2 & (NN - 1)];
            paA2.x = __builtin_bit_cast(unsigned, cvt2(ip.x, ip.y));
            paA2.y = __builtin_bit_cast(unsigned, cvt2(op.x, op.y));
            ip = ((const float2*)igrid)[nB2]; op = ((const float2*)ogrid)[tB2 & (NN - 1)];
            paB2.x = __builtin_bit_cast(unsigned, cvt2(ip.x, ip.y));
            paB2.y = __builtin_bit_cast(unsigned, cvt2(op.x, op.y));
        }
        f16 xA0n = xhf[(size_t)tA2 * OUT_DIM + nl],  xA1n = xhf[(size_t)tA2 * OUT_DIM + 16 + nl];
        f16 xB0n = xhf[(size_t)tB2 * OUT_DIM + nl],  xB1n = xhf[(size_t)tB2 * OUT_DIM + 16 + nl];

        // ---- layer 2 ----
        f16x8 bA0 = *(const f16x8*)&TA[nl * WS + q * 8];
        f16x8 bA1 = *(const f16x8*)&TA[nl * WS + 32 + q * 8];
        f16x8 bB0 = *(const f16x8*)&TB[nl * WS + q * 8];
        f16x8 bB1 = *(const f16x8*)&TB[nl * WS + 32 + q * 8];
        #pragma unroll
        for (int nb = 0; nb < 4; nb++) {
            cA[nb] = __builtin_amdgcn_mfma_f32_16x16x32_f16(bA0, w2f[nb][0], zq, 0, 0, 0);
            cB[nb] = __builtin_amdgcn_mfma_f32_16x16x32_f16(bB0, w2f[nb][0], zq, 0, 0, 0);
            cA[nb] = __builtin_amdgcn_mfma_f32_16x16x32_f16(bA1, w2f[nb][1], cA[nb], 0, 0, 0);
            cB[nb] = __builtin_amdgcn_mfma_f32_16x16x32_f16(bB1, w2f[nb][1], cB[nb], 0, 0, 0);
        }
        #pragma unroll
        for (int r = 0; r < 4; r++) {
            f16x2 hA01 = gelu2b(cA[0][r], cA[1][r], b2p0);
            f16x2 hA23 = gelu2b(cA[2][r], cA[3][r], b2p1);
            f16x2 hB01 = gelu2b(cB[0][r], cB[1][r], b2p0);
            f16x2 hB23 = gelu2b(cB[2][r], cB[3][r], b2p1);
            *(f16x4*)&TA[(q * 4 + r) * WS + nl * 4] = (f16x4){hA01.x, hA01.y, hA23.x, hA23.y};
            *(f16x4*)&TB[(q * 4 + r) * WS + nl * 4] = (f16x4){hB01.x, hB01.y, hB23.x, hB23.y};
        }

        // ---- layer 3 (w3 pre-scaled by 1/16) ----
        bA0 = *(const f16x8*)&TA[nl * WS + q * 8];
        bA1 = *(const f16x8*)&TA[nl * WS + 32 + q * 8];
        bB0 = *(const f16x8*)&TB[nl * WS + q * 8];
        bB1 = *(const f16x8*)&TB[nl * WS + 32 + q * 8];
        f32x4 dA[2], dB[2];
        #pragma unroll
        for (int nb = 0; nb < 2; nb++) {
            dA[nb] = __builtin_amdgcn_mfma_f32_16x16x32_f16(bA0, w3f[nb][0], zq, 0, 0, 0);
            dB[nb] = __builtin_amdgcn_mfma_f32_16x16x32_f16(bB0, w3f[nb][0], zq, 0, 0, 0);
            dA[nb] = __builtin_amdgcn_mfma_f32_16x16x32_f16(bA1, w3f[nb][1], dA[nb], 0, 0, 0);
            dB[nb] = __builtin_amdgcn_mfma_f32_16x16x32_f16(bB1, w3f[nb][1], dB[nb], 0, 0, 0);
        }

        // ---- epilogues: edge-mean (pre-scaled) + bias + residual, LN over 32 ----
        {
            float s0 = dA[0][0] + dA[0][1] + dA[0][2] + dA[0][3];
            float s1 = dA[1][0] + dA[1][1] + dA[1][2] + dA[1][3];
            float u0 = dB[0][0] + dB[0][1] + dB[0][2] + dB[0][3];
            float u1 = dB[1][0] + dB[1][1] + dB[1][2] + dB[1][3];
            s0 += __shfl_xor(s0, 16, 64); s0 += __shfl_xor(s0, 32, 64);
            s1 += __shfl_xor(s1, 16, 64); s1 += __shfl_xor(s1, 32, 64);
            u0 += __shfl_xor(u0, 16, 64); u0 += __shfl_xor(u0, 32, 64);
            u1 += __shfl_xor(u1, 16, 64); u1 += __shfl_xor(u1, 32, 64);

            float oA0 = s0 + b3v[0] + rA0;
            float oA1 = s1 + b3v[1] + rA1;
            float oB0 = u0 + b3v[0] + rB0;
            float oB1 = u1 + b3v[1] + rB1;

            float mA = rowsum16(oA0 + oA1) * (1.0f / 32.0f);
            float mB = rowsum16(oB0 + oB1) * (1.0f / 32.0f);
            float dA0 = oA0 - mA, dA1 = oA1 - mA, dB0 = oB0 - mB, dB1 = oB1 - mB;
            float vA = rowsum16(dA0 * dA0 + dA1 * dA1) * (1.0f / 32.0f);
            float vB = rowsum16(dB0 * dB0 + dB1 * dB1) * (1.0f / 32.0f);
            float rsA = rsqrtf(vA + 1e-5f);
            float rsB = rsqrtf(vB + 1e-5f);

            if (q == 0) {
                float* oa = out + (size_t)tA * OUT_DIM;
                float* ob = out + (size_t)tB * OUT_DIM;
                oa[nl]      = fmaf(dA0 * rsA, g0, be0);
                oa[16 + nl] = fmaf(dA1 * rsA, g1, be1);
                ob[nl]      = fmaf(dB0 * rsB, g0, be0);
                ob[16 + nl] = fmaf(dB1 * rsB, g1, be1);
            }
        }

        // ---- rotate prefetch state ----
        tA = tA2; tB = tB2;
        fyA = fyA2; fyB = fyB2;
        paA = paA2; paB = paB2;
        xA0 = xA0n; xA1 = xA1n; xB0 = xB0n; xB1 = xB1n;
    }
}

extern "C" void kernel_launch(void* const* d_in, const int* in_sizes, int n_in,
                              void* d_out, int out_size, void* d_ws, size_t ws_size,
                              hipStream_t stream) {
    const float* inp   = (const float*)d_in[0];
    const float* igrid = (const float*)d_in[1];
    const float* ogrid = (const float*)d_in[2];
    const int*   nbi   = (const int*)d_in[3];
    const float* Wp1   = (const float*)d_in[4];
    const float* bp1   = (const float*)d_in[5];
    const float* Wp2   = (const float*)d_in[6];
    const float* bp2   = (const float*)d_in[7];
    const float* Wk1   = (const float*)d_in[8];
    const float* bk1   = (const float*)d_in[9];
    const float* Wk2   = (const float*)d_in[10];
    const float* bk2   = (const float*)d_in[11];
    const float* Wk3   = (const float*)d_in[12];
    const float* bk3   = (const float*)d_in[13];
    const float* gma   = (const float*)d_in[14];
    const float* bta   = (const float*)d_in[15];
    float* out = (float*)d_out;
    f16* xhf = (f16*)d_ws;   // B*N*32 f16 = 8 MB

    point_mlp_kernel<<<512, 256, 0, stream>>>(inp, Wp1, bp1, Wp2, bp2, xhf);
    gnn_edge_kernel<<<1024, 256, 0, stream>>>(xhf, igrid, ogrid, nbi,
                                              Wk1, bk1, Wk2, bk2, Wk3, bk3,
                                              gma, bta, out);
}

// Round 7
// 214.931 us; speedup vs baseline: 1.0136x; 1.0136x over previous
//
#include <hip/hip_runtime.h>

#define BB 4
#define NN 32768
#define KKN 16          // neighbors per node
#define IN_DIM 32
#define HID 64
#define OUT_DIM 32
#define KH 64
#define WS 88           // LDS row stride in f16 elems (176 B, 16B-aligned)
#define TOT (BB * NN)   // 131072 = 2^17
#define NWAVES 4096     // grid 1024 blocks x 4 waves

typedef _Float16 f16;
typedef f16 f16x2 __attribute__((ext_vector_type(2)));
typedef f16 f16x4 __attribute__((ext_vector_type(4)));
typedef f16 f16x8 __attribute__((ext_vector_type(8)));
typedef float f32x4 __attribute__((ext_vector_type(4)));
typedef __fp16 hf16x2 __attribute__((ext_vector_type(2)));   // builtin's native type
typedef unsigned int u32x4 __attribute__((ext_vector_type(4)));

#define H2(c) ((f16x2){(f16)(c), (f16)(c)})
#define U2(c) (__builtin_bit_cast(unsigned, H2(c)))

// packed f32->f16x2 convert (v_cvt_pkrtz_f16_f32) -> raw u32 of 2 f16
__device__ __forceinline__ unsigned cvt2u(float a, float b) {
    hf16x2 r = __builtin_amdgcn_cvt_pkrtz(a, b);
    return __builtin_bit_cast(unsigned, r);
}
__device__ __forceinline__ f16x2 cvt2(float a, float b) {
    hf16x2 r = __builtin_amdgcn_cvt_pkrtz(a, b);
    return __builtin_bit_cast(f16x2, r);
}

// ---- single-instruction packed-f16 ops (VOP3P). clang scalarizes _Float16
// vector math into 2x scalar v_*_f16 + hi-half shuffles (~3x instr bloat,
// the R6 counter-implied ~1400 VALU/iter); these pin one ISA instr each.
__device__ __forceinline__ unsigned pk_fma(unsigned a, unsigned b, unsigned c) {
    unsigned d;
    asm("v_pk_fma_f16 %0, %1, %2, %3" : "=v"(d) : "v"(a), "v"(b), "v"(c));
    return d;
}
__device__ __forceinline__ unsigned pk_mul(unsigned a, unsigned b) {
    unsigned d;
    asm("v_pk_mul_f16 %0, %1, %2" : "=v"(d) : "v"(a), "v"(b));
    return d;
}
__device__ __forceinline__ unsigned pk_add(unsigned a, unsigned b) {
    unsigned d;
    asm("v_pk_add_f16 %0, %1, %2" : "=v"(d) : "v"(a), "v"(b));
    return d;
}
__device__ __forceinline__ unsigned pk_max(unsigned a, unsigned b) {
    unsigned d;
    asm("v_pk_max_f16 %0, %1, %2" : "=v"(d) : "v"(a), "v"(b));
    return d;
}
__device__ __forceinline__ unsigned pk_min(unsigned a, unsigned b) {
    unsigned d;
    asm("v_pk_min_f16 %0, %1, %2" : "=v"(d) : "v"(a), "v"(b));
    return d;
}

// loop-invariant gelu constants (compiler hoists into VGPRs once)
struct GeluK {
    unsigned n35, p35, q4, c5, c4, c3, c2, c1, c0, half;
};
__device__ __forceinline__ GeluK gelu_consts() {
    GeluK k;
    k.n35  = U2(-3.5f);        k.p35 = U2(3.5f);
    k.q4   = U2(0.25f);        k.half = U2(0.5f);
    k.c5   = U2(-1.0110344f);  k.c4 = U2(2.85016064f);
    k.c3   = U2(-3.40439040f); k.c2 = U2(2.32402432f);
    k.c1   = U2(-1.04974080f); k.c0 = U2(0.39879504f);
    return k;
}

// packed-f16 polynomial gelu on 2 values in one u32: 11 VOP3P instrs.
// out = x*(0.5 + s*g(t)), s=clamp(x,±3.5), t=(s/4)^2, g Chebyshev deg-5.
__device__ __forceinline__ unsigned gelu2u(unsigned x, const GeluK& k) {
    unsigned s  = pk_min(pk_max(x, k.n35), k.p35);
    unsigned s4 = pk_mul(s, k.q4);
    unsigned t  = pk_mul(s4, s4);
    unsigned g  = pk_fma(k.c5, t, k.c4);
    g = pk_fma(g, t, k.c3);
    g = pk_fma(g, t, k.c2);
    g = pk_fma(g, t, k.c1);
    g = pk_fma(g, t, k.c0);
    unsigned h  = pk_fma(s, g, k.half);
    return pk_mul(x, h);
}
// with packed-f16 bias added post-pack: 13 instrs total incl. cvt
__device__ __forceinline__ unsigned gelu2bu(float a, float b, unsigned bias, const GeluK& k) {
    return gelu2u(pk_add(cvt2u(a, b), bias), k);
}
__device__ __forceinline__ unsigned gelu2nu(float a, float b, const GeluK& k) {
    return gelu2u(cvt2u(a, b), k);
}

// DPP add: v += lane-permuted v (within 16-lane row).
template <int CTRL>
__device__ __forceinline__ float dppadd(float v) {
    union { float f; int i; } u, r;
    u.f = v;
    r.i = __builtin_amdgcn_update_dpp(0, u.i, CTRL, 0xf, 0xf, true);
    return v + r.f;
}
__device__ __forceinline__ float rowsum16(float v) {
    v = dppadd<0xB1>(v);    // quad xor 1
    v = dppadd<0x4E>(v);    // quad xor 2
    v = dppadd<0x124>(v);   // row rotate 4
    v = dppadd<0x128>(v);   // row rotate 8
    return v;
}

// ---------------- Kernel A: point MLP via MFMA (persistent) ----------------
__global__ __launch_bounds__(256) void point_mlp_kernel(
    const float* __restrict__ inp, const float* __restrict__ Wp1,
    const float* __restrict__ bp1, const float* __restrict__ Wp2,
    const float* __restrict__ bp2, f16* __restrict__ xhf)
{
    __shared__ __align__(16) f16 hb[4][16 * WS];
    const int tid = threadIdx.x, w = tid >> 6, lane = tid & 63;
    const int q = lane >> 4, nl = lane & 15;
    const GeluK gk = gelu_consts();

    f16x8 w1f[4];
    #pragma unroll
    for (int nb = 0; nb < 4; nb++)
        #pragma unroll
        for (int j = 0; j < 8; j++)
            w1f[nb][j] = (f16)Wp1[(q * 8 + j) * HID + nb * 16 + nl];
    f16x8 w2f[2][2];        // rows pre-permuted by p_inv(k) = (k&3)*16 + k/4
    #pragma unroll
    for (int nb = 0; nb < 2; nb++)
        #pragma unroll
        for (int c = 0; c < 2; c++)
            #pragma unroll
            for (int j = 0; j < 8; j++) {
                int k = c * 32 + q * 8 + j, kp = ((k & 3) << 4) | (k >> 2);
                w2f[nb][c][j] = (f16)Wp2[kp * OUT_DIM + nb * 16 + nl];
            }
    // packed bias for L1 (re-injected post-pack), f32 bias for L2 C-init
    const unsigned b1q0 = cvt2u(bp1[nl],      bp1[16 + nl]);
    const unsigned b1q1 = cvt2u(bp1[32 + nl], bp1[48 + nl]);
    float b2v[2];
    b2v[0] = bp2[nl]; b2v[1] = bp2[16 + nl];
    const f32x4 zq = (f32x4){0.f, 0.f, 0.f, 0.f};

    const int gw = blockIdx.x * 4 + w;
    const int nw = gridDim.x * 4;

    for (int t = gw; t < TOT / 16; t += nw) {
        const int R = t * 16;
        const float* ap = inp + (size_t)(R + nl) * IN_DIM + q * 8;
        float4 av0 = *(const float4*)ap, av1 = *(const float4*)(ap + 4);
        f16x2 p01 = cvt2(av0.x, av0.y);
        f16x2 p23 = cvt2(av0.z, av0.w);
        f16x2 p45 = cvt2(av1.x, av1.y);
        f16x2 p67 = cvt2(av1.z, av1.w);
        f16x8 af = (f16x8){p01.x, p01.y, p23.x, p23.y, p45.x, p45.y, p67.x, p67.y};

        f32x4 acc[4];
        #pragma unroll
        for (int nb = 0; nb < 4; nb++)
            acc[nb] = __builtin_amdgcn_mfma_f32_16x16x32_f16(af, w1f[nb], zq, 0, 0, 0);

        #pragma unroll
        for (int r = 0; r < 4; r++) {
            unsigned h01 = gelu2bu(acc[0][r], acc[1][r], b1q0, gk);
            unsigned h23 = gelu2bu(acc[2][r], acc[3][r], b1q1, gk);
            *(uint2*)&hb[w][(q * 4 + r) * WS + nl * 4] = (uint2){h01, h23};
        }
        f16x8 a0 = *(const f16x8*)&hb[w][nl * WS + q * 8];
        f16x8 a1 = *(const f16x8*)&hb[w][nl * WS + 32 + q * 8];
        f32x4 a2[2];
        #pragma unroll
        for (int nb = 0; nb < 2; nb++) {
            a2[nb] = (f32x4){b2v[nb], b2v[nb], b2v[nb], b2v[nb]};
            a2[nb] = __builtin_amdgcn_mfma_f32_16x16x32_f16(a0, w2f[nb][0], a2[nb], 0, 0, 0);
            a2[nb] = __builtin_amdgcn_mfma_f32_16x16x32_f16(a1, w2f[nb][1], a2[nb], 0, 0, 0);
        }
        #pragma unroll
        for (int r = 0; r < 4; r++)
            #pragma unroll
            for (int nb = 0; nb < 2; nb++)
                xhf[(size_t)(R + q * 4 + r) * OUT_DIM + nb * 16 + nl] = (f16)a2[nb][r];
    }
}

// ---------------- Kernel B: edge MLP, 2 nodes/iter ----------------
// R6 structure: gather lanes in MFMA A-frag order (prefetched register IS
// the L1 A-operand; no LDS commit). LDS only for L1->L2, L2->L3 transposes.
// Gelu: single-instruction v_pk_* asm core (13 instrs/pair).
__global__ __launch_bounds__(256) void gnn_edge_kernel(
    const f16*   __restrict__ xhf,
    const float* __restrict__ igrid, const float* __restrict__ ogrid,
    const int*   __restrict__ nbi,
    const float* __restrict__ Wk1, const float* __restrict__ bk1,
    const float* __restrict__ Wk2, const float* __restrict__ bk2,
    const float* __restrict__ Wk3, const float* __restrict__ bk3,
    const float* __restrict__ gma, const float* __restrict__ bta,
    float* __restrict__ out)
{
    __shared__ __align__(16) f16 tile[8][16 * WS];   // 2 h-tiles per wave (22.5 KB)

    const int tid = threadIdx.x, w = tid >> 6, lane = tid & 63;
    const int q = lane >> 4, nl = lane & 15;
    f16* __restrict__ TA = tile[w * 2];
    f16* __restrict__ TB = tile[w * 2 + 1];
    const GeluK gk = gelu_consts();

    // ---- weight B-frags in registers ----
    f16x8 w1f[4][2], w2f[4][2], w3f[2][2];
    #pragma unroll
    for (int nb = 0; nb < 4; nb++) {
        #pragma unroll
        for (int j = 0; j < 8; j++) {
            w1f[nb][0][j] = (f16)Wk1[(4 + q * 8 + j) * KH + nb * 16 + nl];
            float v1 = 0.0f;
            if (j < 4 && q == 0) v1 = Wk1[j * KH + nb * 16 + nl];
            w1f[nb][1][j] = (f16)v1;
        }
        #pragma unroll
        for (int c = 0; c < 2; c++)
            #pragma unroll
            for (int j = 0; j < 8; j++) {
                int k = c * 32 + q * 8 + j, kp = ((k & 3) << 4) | (k >> 2);
                w2f[nb][c][j] = (f16)Wk2[kp * KH + nb * 16 + nl];
            }
    }
    // w3 pre-scaled by 1/16: folds the edge-mean into the matmul
    #pragma unroll
    for (int nb = 0; nb < 2; nb++)
        #pragma unroll
        for (int c = 0; c < 2; c++)
            #pragma unroll
            for (int j = 0; j < 8; j++) {
                int k = c * 32 + q * 8 + j, kp = ((k & 3) << 4) | (k >> 2);
                w3f[nb][c][j] = (f16)(Wk3[kp * OUT_DIM + nb * 16 + nl] * 0.0625f);
            }

    // packed-f16 bias pairs for gelu re-injection (per-lane nl only)
    const unsigned b1q0 = cvt2u(bk1[nl],      bk1[16 + nl]);
    const unsigned b1q1 = cvt2u(bk1[32 + nl], bk1[48 + nl]);
    const unsigned b2q0 = cvt2u(bk2[nl],      bk2[16 + nl]);
    const unsigned b2q1 = cvt2u(bk2[32 + nl], bk2[48 + nl]);
    float b3v[2];
    b3v[0] = bk3[nl]; b3v[1] = bk3[16 + nl];
    const float g0 = gma[nl], g1 = gma[16 + nl], be0 = bta[nl], be1 = bta[16 + nl];

    const f32x4 zq = (f32x4){0.f, 0.f, 0.f, 0.f};

    const int gw = blockIdx.x * 4 + w;

    // ---- prologue prefetch (pair 0) ----
    // lane (q,nl): neighbor row = nbi[node*16 + nl], bytes q*16..q*16+15
    int tA = gw, tB = gw + NWAVES;
    int nA = nbi[(tA & (NN - 1)) * KKN + nl];
    int nB = nbi[(tB & (NN - 1)) * KKN + nl];
    uint4 fyA = ((const uint4*)(xhf + ((size_t)((tA >> 15) * NN + nA)) * OUT_DIM))[q];
    uint4 fyB = ((const uint4*)(xhf + ((size_t)((tB >> 15) * NN + nB)) * OUT_DIM))[q];
    uint2 paA, paB;                       // packed pos feats [ip.x ip.y | op.x op.y]
    if (q == 0) {
        float2 ip, op;
        ip = ((const float2*)igrid)[nA]; op = ((const float2*)ogrid)[tA & (NN - 1)];
        paA.x = cvt2u(ip.x, ip.y); paA.y = cvt2u(op.x, op.y);
        ip = ((const float2*)igrid)[nB]; op = ((const float2*)ogrid)[tB & (NN - 1)];
        paB.x = cvt2u(ip.x, ip.y); paB.y = cvt2u(op.x, op.y);
    }
    f16 xA0 = xhf[(size_t)tA * OUT_DIM + nl],      xA1 = xhf[(size_t)tA * OUT_DIM + 16 + nl];
    f16 xB0 = xhf[(size_t)tB * OUT_DIM + nl],      xB1 = xhf[(size_t)tB * OUT_DIM + 16 + nl];

    #pragma unroll 1
    for (int it = 0; it < TOT / (2 * NWAVES); ++it) {
        const float rA0 = (float)xA0, rA1 = (float)xA1, rB0 = (float)xB0, rB1 = (float)xB1;

        // ---- next pair indices (wraparound, always valid) ----
        const int tA2 = (tA + 2 * NWAVES) & (TOT - 1);
        const int tB2 = tA2 + NWAVES;
        const int nA2 = nbi[(tA2 & (NN - 1)) * KKN + nl];
        const int nB2 = nbi[(tB2 & (NN - 1)) * KKN + nl];

        // ---- layer 1: A-operands straight from prefetched registers ----
        f16x8 aA0 = __builtin_bit_cast(f16x8, fyA);
        f16x8 aB0 = __builtin_bit_cast(f16x8, fyB);
        u32x4 uA1 = (u32x4){q == 0 ? paA.x : 0u, q == 0 ? paA.y : 0u, 0u, 0u};
        u32x4 uB1 = (u32x4){q == 0 ? paB.x : 0u, q == 0 ? paB.y : 0u, 0u, 0u};
        f16x8 aA1 = __builtin_bit_cast(f16x8, uA1);
        f16x8 aB1 = __builtin_bit_cast(f16x8, uB1);

        f32x4 cA[4], cB[4];
        #pragma unroll
        for (int nb = 0; nb < 4; nb++) {
            cA[nb] = __builtin_amdgcn_mfma_f32_16x16x32_f16(aA0, w1f[nb][0], zq, 0, 0, 0);
            cB[nb] = __builtin_amdgcn_mfma_f32_16x16x32_f16(aB0, w1f[nb][0], zq, 0, 0, 0);
            cA[nb] = __builtin_amdgcn_mfma_f32_16x16x32_f16(aA1, w1f[nb][1], cA[nb], 0, 0, 0);
            cB[nb] = __builtin_amdgcn_mfma_f32_16x16x32_f16(aB1, w1f[nb][1], cB[nb], 0, 0, 0);
        }
        #pragma unroll
        for (int r = 0; r < 4; r++) {
            unsigned hA01 = gelu2bu(cA[0][r], cA[1][r], b1q0, gk);
            unsigned hA23 = gelu2bu(cA[2][r], cA[3][r], b1q1, gk);
            unsigned hB01 = gelu2bu(cB[0][r], cB[1][r], b1q0, gk);
            unsigned hB23 = gelu2bu(cB[2][r], cB[3][r], b1q1, gk);
            *(uint2*)&TA[(q * 4 + r) * WS + nl * 4] = (uint2){hA01, hA23};
            *(uint2*)&TB[(q * 4 + r) * WS + nl * 4] = (uint2){hB01, hB23};
        }

        // ---- issue next pair's gathers (overlap layers 2-3) ----
        uint4 fyA2 = ((const uint4*)(xhf + ((size_t)((tA2 >> 15) * NN + nA2)) * OUT_DIM))[q];
        uint4 fyB2 = ((const uint4*)(xhf + ((size_t)((tB2 >> 15) * NN + nB2)) * OUT_DIM))[q];
        uint2 paA2, paB2;
        if (q == 0) {
            float2 ip, op;
            ip = ((const float2*)igrid)[nA2]; op = ((const float2*)ogrid)[tA2 & (NN - 1)];
            paA2.x = cvt2u(ip.x, ip.y); paA2.y = cvt2u(op.x, op.y);
            ip = ((const float2*)igrid)[nB2]; op = ((const float2*)ogrid)[tB2 & (NN - 1)];
            paB2.x = cvt2u(ip.x, ip.y); paB2.y = cvt2u(op.x, op.y);
        }
        f16 xA0n = xhf[(size_t)tA2 * OUT_DIM + nl],  xA1n = xhf[(size_t)tA2 * OUT_DIM + 16 + nl];
        f16 xB0n = xhf[(size_t)tB2 * OUT_DIM + nl],  xB1n = xhf[(size_t)tB2 * OUT_DIM + 16 + nl];

        // ---- layer 2 ----
        f16x8 bA0 = *(const f16x8*)&TA[nl * WS + q * 8];
        f16x8 bA1 = *(const f16x8*)&TA[nl * WS + 32 + q * 8];
        f16x8 bB0 = *(const f16x8*)&TB[nl * WS + q * 8];
        f16x8 bB1 = *(const f16x8*)&TB[nl * WS + 32 + q * 8];
        #pragma unroll
        for (int nb = 0; nb < 4; nb++) {
            cA[nb] = __builtin_amdgcn_mfma_f32_16x16x32_f16(bA0, w2f[nb][0], zq, 0, 0, 0);
            cB[nb] = __builtin_amdgcn_mfma_f32_16x16x32_f16(bB0, w2f[nb][0], zq, 0, 0, 0);
            cA[nb] = __builtin_amdgcn_mfma_f32_16x16x32_f16(bA1, w2f[nb][1], cA[nb], 0, 0, 0);
            cB[nb] = __builtin_amdgcn_mfma_f32_16x16x32_f16(bB1, w2f[nb][1], cB[nb], 0, 0, 0);
        }
        #pragma unroll
        for (int r = 0; r < 4; r++) {
            unsigned hA01 = gelu2bu(cA[0][r], cA[1][r], b2q0, gk);
            unsigned hA23 = gelu2bu(cA[2][r], cA[3][r], b2q1, gk);
            unsigned hB01 = gelu2bu(cB[0][r], cB[1][r], b2q0, gk);
            unsigned hB23 = gelu2bu(cB[2][r], cB[3][r], b2q1, gk);
            *(uint2*)&TA[(q * 4 + r) * WS + nl * 4] = (uint2){hA01, hA23};
            *(uint2*)&TB[(q * 4 + r) * WS + nl * 4] = (uint2){hB01, hB23};
        }

        // ---- layer 3 (w3 pre-scaled by 1/16) ----
        bA0 = *(const f16x8*)&TA[nl * WS + q * 8];
        bA1 = *(const f16x8*)&TA[nl * WS + 32 + q * 8];
        bB0 = *(const f16x8*)&TB[nl * WS + q * 8];
        bB1 = *(const f16x8*)&TB[nl * WS + 32 + q * 8];
        f32x4 dA[2], dB[2];
        #pragma unroll
        for (int nb = 0; nb < 2; nb++) {
            dA[nb] = __builtin_amdgcn_mfma_f32_16x16x32_f16(bA0, w3f[nb][0], zq, 0, 0, 0);
            dB[nb] = __builtin_amdgcn_mfma_f32_16x16x32_f16(bB0, w3f[nb][0], zq, 0, 0, 0);
            dA[nb] = __builtin_amdgcn_mfma_f32_16x16x32_f16(bA1, w3f[nb][1], dA[nb], 0, 0, 0);
            dB[nb] = __builtin_amdgcn_mfma_f32_16x16x32_f16(bB1, w3f[nb][1], dB[nb], 0, 0, 0);
        }

        // ---- epilogues: edge-mean (pre-scaled) + bias + residual, LN over 32 ----
        {
            float s0 = dA[0][0] + dA[0][1] + dA[0][2] + dA[0][3];
            float s1 = dA[1][0] + dA[1][1] + dA[1][2] + dA[1][3];
            float u0 = dB[0][0] + dB[0][1] + dB[0][2] + dB[0][3];
            float u1 = dB[1][0] + dB[1][1] + dB[1][2] + dB[1][3];
            s0 += __shfl_xor(s0, 16, 64); s0 += __shfl_xor(s0, 32, 64);
            s1 += __shfl_xor(s1, 16, 64); s1 += __shfl_xor(s1, 32, 64);
            u0 += __shfl_xor(u0, 16, 64); u0 += __shfl_xor(u0, 32, 64);
            u1 += __shfl_xor(u1, 16, 64); u1 += __shfl_xor(u1, 32, 64);

            float oA0 = s0 + b3v[0] + rA0;
            float oA1 = s1 + b3v[1] + rA1;
            float oB0 = u0 + b3v[0] + rB0;
            float oB1 = u1 + b3v[1] + rB1;

            float mA = rowsum16(oA0 + oA1) * (1.0f / 32.0f);
            float mB = rowsum16(oB0 + oB1) * (1.0f / 32.0f);
            float dA0 = oA0 - mA, dA1 = oA1 - mA, dB0 = oB0 - mB, dB1 = oB1 - mB;
            float vA = rowsum16(dA0 * dA0 + dA1 * dA1) * (1.0f / 32.0f);
            float vB = rowsum16(dB0 * dB0 + dB1 * dB1) * (1.0f / 32.0f);
            float rsA = rsqrtf(vA + 1e-5f);
            float rsB = rsqrtf(vB + 1e-5f);

            if (q == 0) {
                float* oa = out + (size_t)tA * OUT_DIM;
                float* ob = out + (size_t)tB * OUT_DIM;
                oa[nl]      = fmaf(dA0 * rsA, g0, be0);
                oa[16 + nl] = fmaf(dA1 * rsA, g1, be1);
                ob[nl]      = fmaf(dB0 * rsB, g0, be0);
                ob[16 + nl] = fmaf(dB1 * rsB, g1, be1);
            }
        }

        // ---- rotate prefetch state ----
        tA = tA2; tB = tB2;
        fyA = fyA2; fyB = fyB2;
        paA = paA2; paB = paB2;
        xA0 = xA0n; xA1 = xA1n; xB0 = xB0n; xB1 = xB1n;
    }
}

extern "C" void kernel_launch(void* const* d_in, const int* in_sizes, int n_in,
                              void* d_out, int out_size, void* d_ws, size_t ws_size,
                              hipStream_t stream) {
    const float* inp   = (const float*)d_in[0];
    const float* igrid = (const float*)d_in[1];
    const float* ogrid = (const float*)d_in[2];
    const int*   nbi   = (const int*)d_in[3];
    const float* Wp1   = (const float*)d_in[4];
    const float* bp1   = (const float*)d_in[5];
    const float* Wp2   = (const float*)d_in[6];
    const float* bp2   = (const float*)d_in[7];
    const float* Wk1   = (const float*)d_in[8];
    const float* bk1   = (const float*)d_in[9];
    const float* Wk2   = (const float*)d_in[10];
    const float* bk2   = (const float*)d_in[11];
    const float* Wk3   = (const float*)d_in[12];
    const float* bk3   = (const float*)d_in[13];
    const float* gma   = (const float*)d_in[14];
    const float* bta   = (const float*)d_in[15];
    float* out = (float*)d_out;
    f16* xhf = (f16*)d_ws;   // B*N*32 f16 = 8 MB

    point_mlp_kernel<<<512, 256, 0, stream>>>(inp, Wp1, bp1, Wp2, bp2, xhf);
    gnn_edge_kernel<<<1024, 256, 0, stream>>>(xhf, igrid, ogrid, nbi,
                                              Wk1, bk1, Wk2, bk2, Wk3, bk3,
                                              gma, bta, out);
}

// Round 8
// 210.230 us; speedup vs baseline: 1.0363x; 1.0224x over previous
//
#include <hip/hip_runtime.h>

#define BB 4
#define NN 32768
#define KKN 16          // neighbors per node
#define IN_DIM 32
#define HID 64
#define OUT_DIM 32
#define KH 64
#define WS 72           // LDS row stride in f16 elems (144 B; reads 2-way=free)
#define TOT (BB * NN)   // 131072 = 2^17
#define NWAVES 4096     // grid 1024 blocks x 4 waves

typedef _Float16 f16;
typedef f16 f16x2 __attribute__((ext_vector_type(2)));
typedef f16 f16x4 __attribute__((ext_vector_type(4)));
typedef f16 f16x8 __attribute__((ext_vector_type(8)));
typedef float f32x4 __attribute__((ext_vector_type(4)));
typedef __fp16 hf16x2 __attribute__((ext_vector_type(2)));   // builtin's native type
typedef unsigned int u32x4 __attribute__((ext_vector_type(4)));

#define H2(c) ((f16x2){(f16)(c), (f16)(c)})
#define U2(c) (__builtin_bit_cast(unsigned, H2(c)))

// packed f32->f16x2 convert (v_cvt_pkrtz_f16_f32) -> raw u32 of 2 f16
__device__ __forceinline__ unsigned cvt2u(float a, float b) {
    hf16x2 r = __builtin_amdgcn_cvt_pkrtz(a, b);
    return __builtin_bit_cast(unsigned, r);
}
__device__ __forceinline__ f16x2 cvt2(float a, float b) {
    hf16x2 r = __builtin_amdgcn_cvt_pkrtz(a, b);
    return __builtin_bit_cast(f16x2, r);
}

// ---- single-instruction packed-f16 ops (VOP3P) ----
__device__ __forceinline__ unsigned pk_fma(unsigned a, unsigned b, unsigned c) {
    unsigned d;
    asm("v_pk_fma_f16 %0, %1, %2, %3" : "=v"(d) : "v"(a), "v"(b), "v"(c));
    return d;
}
__device__ __forceinline__ unsigned pk_mul(unsigned a, unsigned b) {
    unsigned d;
    asm("v_pk_mul_f16 %0, %1, %2" : "=v"(d) : "v"(a), "v"(b));
    return d;
}
__device__ __forceinline__ unsigned pk_add(unsigned a, unsigned b) {
    unsigned d;
    asm("v_pk_add_f16 %0, %1, %2" : "=v"(d) : "v"(a), "v"(b));
    return d;
}
__device__ __forceinline__ unsigned pk_max(unsigned a, unsigned b) {
    unsigned d;
    asm("v_pk_max_f16 %0, %1, %2" : "=v"(d) : "v"(a), "v"(b));
    return d;
}
__device__ __forceinline__ unsigned pk_min(unsigned a, unsigned b) {
    unsigned d;
    asm("v_pk_min_f16 %0, %1, %2" : "=v"(d) : "v"(a), "v"(b));
    return d;
}

struct GeluK {
    unsigned n35, p35, q4, c5, c4, c3, c2, c1, c0, half;
};
__device__ __forceinline__ GeluK gelu_consts() {
    GeluK k;
    k.n35  = U2(-3.5f);        k.p35 = U2(3.5f);
    k.q4   = U2(0.25f);        k.half = U2(0.5f);
    k.c5   = U2(-1.0110344f);  k.c4 = U2(2.85016064f);
    k.c3   = U2(-3.40439040f); k.c2 = U2(2.32402432f);
    k.c1   = U2(-1.04974080f); k.c0 = U2(0.39879504f);
    return k;
}

// packed-f16 polynomial gelu on 2 values in one u32.
__device__ __forceinline__ unsigned gelu2u(unsigned x, const GeluK& k) {
    unsigned s  = pk_min(pk_max(x, k.n35), k.p35);
    unsigned s4 = pk_mul(s, k.q4);
    unsigned t  = pk_mul(s4, s4);
    unsigned g  = pk_fma(k.c5, t, k.c4);
    g = pk_fma(g, t, k.c3);
    g = pk_fma(g, t, k.c2);
    g = pk_fma(g, t, k.c1);
    g = pk_fma(g, t, k.c0);
    unsigned h  = pk_fma(s, g, k.half);
    return pk_mul(x, h);
}
__device__ __forceinline__ unsigned gelu2bu(float a, float b, unsigned bias, const GeluK& k) {
    return gelu2u(pk_add(cvt2u(a, b), bias), k);
}

// DPP add: v += lane-permuted v (within 16-lane row).
template <int CTRL>
__device__ __forceinline__ float dppadd(float v) {
    union { float f; int i; } u, r;
    u.f = v;
    r.i = __builtin_amdgcn_update_dpp(0, u.i, CTRL, 0xf, 0xf, true);
    return v + r.f;
}
__device__ __forceinline__ float rowsum16(float v) {
    v = dppadd<0xB1>(v);    // quad xor 1
    v = dppadd<0x4E>(v);    // quad xor 2
    v = dppadd<0x124>(v);   // row rotate 4
    v = dppadd<0x128>(v);   // row rotate 8
    return v;
}

// ---------------- Kernel A: point MLP via MFMA (persistent) ----------------
__global__ __launch_bounds__(256) void point_mlp_kernel(
    const float* __restrict__ inp, const float* __restrict__ Wp1,
    const float* __restrict__ bp1, const float* __restrict__ Wp2,
    const float* __restrict__ bp2, f16* __restrict__ xhf)
{
    __shared__ __align__(16) f16 hb[4][16 * WS];
    const int tid = threadIdx.x, w = tid >> 6, lane = tid & 63;
    const int q = lane >> 4, nl = lane & 15;
    const GeluK gk = gelu_consts();

    f16x8 w1f[4];
    #pragma unroll
    for (int nb = 0; nb < 4; nb++)
        #pragma unroll
        for (int j = 0; j < 8; j++)
            w1f[nb][j] = (f16)Wp1[(q * 8 + j) * HID + nb * 16 + nl];
    f16x8 w2f[2][2];        // rows pre-permuted by p_inv(k) = (k&3)*16 + k/4
    #pragma unroll
    for (int nb = 0; nb < 2; nb++)
        #pragma unroll
        for (int c = 0; c < 2; c++)
            #pragma unroll
            for (int j = 0; j < 8; j++) {
                int k = c * 32 + q * 8 + j, kp = ((k & 3) << 4) | (k >> 2);
                w2f[nb][c][j] = (f16)Wp2[kp * OUT_DIM + nb * 16 + nl];
            }
    const unsigned b1q0 = cvt2u(bp1[nl],      bp1[16 + nl]);
    const unsigned b1q1 = cvt2u(bp1[32 + nl], bp1[48 + nl]);
    float b2v[2];
    b2v[0] = bp2[nl]; b2v[1] = bp2[16 + nl];
    const f32x4 zq = (f32x4){0.f, 0.f, 0.f, 0.f};

    const int gw = blockIdx.x * 4 + w;
    const int nw = gridDim.x * 4;

    for (int t = gw; t < TOT / 16; t += nw) {
        const int R = t * 16;
        const float* ap = inp + (size_t)(R + nl) * IN_DIM + q * 8;
        float4 av0 = *(const float4*)ap, av1 = *(const float4*)(ap + 4);
        f16x2 p01 = cvt2(av0.x, av0.y);
        f16x2 p23 = cvt2(av0.z, av0.w);
        f16x2 p45 = cvt2(av1.x, av1.y);
        f16x2 p67 = cvt2(av1.z, av1.w);
        f16x8 af = (f16x8){p01.x, p01.y, p23.x, p23.y, p45.x, p45.y, p67.x, p67.y};

        f32x4 acc[4];
        #pragma unroll
        for (int nb = 0; nb < 4; nb++)
            acc[nb] = __builtin_amdgcn_mfma_f32_16x16x32_f16(af, w1f[nb], zq, 0, 0, 0);

        #pragma unroll
        for (int r = 0; r < 4; r++) {
            unsigned h01 = gelu2bu(acc[0][r], acc[1][r], b1q0, gk);
            unsigned h23 = gelu2bu(acc[2][r], acc[3][r], b1q1, gk);
            *(uint2*)&hb[w][(q * 4 + r) * WS + nl * 4] = (uint2){h01, h23};
        }
        f16x8 a0 = *(const f16x8*)&hb[w][nl * WS + q * 8];
        f16x8 a1 = *(const f16x8*)&hb[w][nl * WS + 32 + q * 8];
        f32x4 a2[2];
        #pragma unroll
        for (int nb = 0; nb < 2; nb++) {
            a2[nb] = (f32x4){b2v[nb], b2v[nb], b2v[nb], b2v[nb]};
            a2[nb] = __builtin_amdgcn_mfma_f32_16x16x32_f16(a0, w2f[nb][0], a2[nb], 0, 0, 0);
            a2[nb] = __builtin_amdgcn_mfma_f32_16x16x32_f16(a1, w2f[nb][1], a2[nb], 0, 0, 0);
        }
        #pragma unroll
        for (int r = 0; r < 4; r++)
            #pragma unroll
            for (int nb = 0; nb < 2; nb++)
                xhf[(size_t)(R + q * 4 + r) * OUT_DIM + nb * 16 + nl] = (f16)a2[nb][r];
    }
}

// ---------------- Kernel B: edge MLP, 2 nodes/iter, weights in LDS ----------------
// Theory (R8): VGPR_Count=104 hid ~90 AGPRs (unified file) -> ~190 total regs
// -> 2 waves/SIMD -> latency-starved (occupancy counter ~20% across all rounds).
// Fix: the 20 weight B-frags (80 regs, identical across waves) live in a
// 20 KB per-block LDS table, read via conflict-free ds_read_b128 at use.
// Register demand drops to ~100 total -> 4 waves/SIMD; LDS 38.9 KB -> 4 blocks/CU.
__global__ __launch_bounds__(256) void gnn_edge_kernel(
    const f16*   __restrict__ xhf,
    const float* __restrict__ igrid, const float* __restrict__ ogrid,
    const int*   __restrict__ nbi,
    const float* __restrict__ Wk1, const float* __restrict__ bk1,
    const float* __restrict__ Wk2, const float* __restrict__ bk2,
    const float* __restrict__ Wk3, const float* __restrict__ bk3,
    const float* __restrict__ gma, const float* __restrict__ bta,
    float* __restrict__ out)
{
    __shared__ __align__(16) f16 tile[8][16 * WS];   // 2 h-tiles/wave, 18.4 KB
    __shared__ __align__(16) f16 wf[20][64][8];      // 20 B-frags, 20.5 KB

    const int tid = threadIdx.x, w = tid >> 6, lane = tid & 63;
    const int q = lane >> 4, nl = lane & 15;
    f16* __restrict__ TA = tile[w * 2];
    f16* __restrict__ TB = tile[w * 2 + 1];
    const GeluK gk = gelu_consts();

    // ---- build weight-frag table: wave w owns frags 5w..5w+4; each lane
    // writes its own 16 B (frag data depends only on lane) ----
    #pragma unroll 1
    for (int f = w * 5; f < w * 5 + 5; ++f) {
        f16x8 v;
        if (f < 4) {                     // w1[nb][0]
            int nb = f;
            #pragma unroll
            for (int j = 0; j < 8; j++)
                v[j] = (f16)Wk1[(4 + q * 8 + j) * KH + nb * 16 + nl];
        } else if (f < 8) {              // w1[nb][1] (pos rows; q==0, j<4 only)
            int nb = f - 4;
            #pragma unroll
            for (int j = 0; j < 8; j++) {
                float x = 0.0f;
                if (j < 4 && q == 0) x = Wk1[j * KH + nb * 16 + nl];
                v[j] = (f16)x;
            }
        } else if (f < 16) {             // w2[nb][c], c = (f-8)/4
            int nb = (f - 8) & 3, c = (f - 8) >> 2;
            #pragma unroll
            for (int j = 0; j < 8; j++) {
                int k = c * 32 + q * 8 + j, kp = ((k & 3) << 4) | (k >> 2);
                v[j] = (f16)Wk2[kp * KH + nb * 16 + nl];
            }
        } else {                         // w3[nb][c] pre-scaled by 1/16
            int nb = (f - 16) & 1, c = (f - 16) >> 1;
            #pragma unroll
            for (int j = 0; j < 8; j++) {
                int k = c * 32 + q * 8 + j, kp = ((k & 3) << 4) | (k >> 2);
                v[j] = (f16)(Wk3[kp * OUT_DIM + nb * 16 + nl] * 0.0625f);
            }
        }
        *(f16x8*)&wf[f][lane][0] = v;
    }
    __syncthreads();   // one-time: weight table ready
    #define WFRAG(f) (*(const f16x8*)&wf[(f)][lane][0])

    // packed-f16 bias pairs for gelu re-injection
    const unsigned b1q0 = cvt2u(bk1[nl],      bk1[16 + nl]);
    const unsigned b1q1 = cvt2u(bk1[32 + nl], bk1[48 + nl]);
    const unsigned b2q0 = cvt2u(bk2[nl],      bk2[16 + nl]);
    const unsigned b2q1 = cvt2u(bk2[32 + nl], bk2[48 + nl]);
    float b3v[2];
    b3v[0] = bk3[nl]; b3v[1] = bk3[16 + nl];
    const float g0 = gma[nl], g1 = gma[16 + nl], be0 = bta[nl], be1 = bta[16 + nl];

    const f32x4 zq = (f32x4){0.f, 0.f, 0.f, 0.f};

    const int gw = blockIdx.x * 4 + w;

    // ---- prologue prefetch (pair 0): gather lanes in A-frag order ----
    int tA = gw, tB = gw + NWAVES;
    int nA = nbi[(tA & (NN - 1)) * KKN + nl];
    int nB = nbi[(tB & (NN - 1)) * KKN + nl];
    uint4 fyA = ((const uint4*)(xhf + ((size_t)((tA >> 15) * NN + nA)) * OUT_DIM))[q];
    uint4 fyB = ((const uint4*)(xhf + ((size_t)((tB >> 15) * NN + nB)) * OUT_DIM))[q];
    uint2 paA, paB;
    if (q == 0) {
        float2 ip, op;
        ip = ((const float2*)igrid)[nA]; op = ((const float2*)ogrid)[tA & (NN - 1)];
        paA.x = cvt2u(ip.x, ip.y); paA.y = cvt2u(op.x, op.y);
        ip = ((const float2*)igrid)[nB]; op = ((const float2*)ogrid)[tB & (NN - 1)];
        paB.x = cvt2u(ip.x, ip.y); paB.y = cvt2u(op.x, op.y);
    }
    f16 xA0 = xhf[(size_t)tA * OUT_DIM + nl],      xA1 = xhf[(size_t)tA * OUT_DIM + 16 + nl];
    f16 xB0 = xhf[(size_t)tB * OUT_DIM + nl],      xB1 = xhf[(size_t)tB * OUT_DIM + 16 + nl];

    #pragma unroll 1
    for (int it = 0; it < TOT / (2 * NWAVES); ++it) {
        const float rA0 = (float)xA0, rA1 = (float)xA1, rB0 = (float)xB0, rB1 = (float)xB1;

        const int tA2 = (tA + 2 * NWAVES) & (TOT - 1);
        const int tB2 = tA2 + NWAVES;
        const int nA2 = nbi[(tA2 & (NN - 1)) * KKN + nl];
        const int nB2 = nbi[(tB2 & (NN - 1)) * KKN + nl];

        // ---- layer 1: A-operands straight from prefetched registers ----
        f16x8 aA0 = __builtin_bit_cast(f16x8, fyA);
        f16x8 aB0 = __builtin_bit_cast(f16x8, fyB);
        u32x4 uA1 = (u32x4){q == 0 ? paA.x : 0u, q == 0 ? paA.y : 0u, 0u, 0u};
        u32x4 uB1 = (u32x4){q == 0 ? paB.x : 0u, q == 0 ? paB.y : 0u, 0u, 0u};
        f16x8 aA1 = __builtin_bit_cast(f16x8, uA1);
        f16x8 aB1 = __builtin_bit_cast(f16x8, uB1);

        f32x4 cA[4], cB[4];
        #pragma unroll
        for (int nb = 0; nb < 4; nb++) {
            f16x8 W0 = WFRAG(nb);
            cA[nb] = __builtin_amdgcn_mfma_f32_16x16x32_f16(aA0, W0, zq, 0, 0, 0);
            cB[nb] = __builtin_amdgcn_mfma_f32_16x16x32_f16(aB0, W0, zq, 0, 0, 0);
        }
        #pragma unroll
        for (int nb = 0; nb < 4; nb++) {
            f16x8 W1 = WFRAG(4 + nb);
            cA[nb] = __builtin_amdgcn_mfma_f32_16x16x32_f16(aA1, W1, cA[nb], 0, 0, 0);
            cB[nb] = __builtin_amdgcn_mfma_f32_16x16x32_f16(aB1, W1, cB[nb], 0, 0, 0);
        }
        #pragma unroll
        for (int r = 0; r < 4; r++) {
            unsigned hA01 = gelu2bu(cA[0][r], cA[1][r], b1q0, gk);
            unsigned hA23 = gelu2bu(cA[2][r], cA[3][r], b1q1, gk);
            unsigned hB01 = gelu2bu(cB[0][r], cB[1][r], b1q0, gk);
            unsigned hB23 = gelu2bu(cB[2][r], cB[3][r], b1q1, gk);
            *(uint2*)&TA[(q * 4 + r) * WS + nl * 4] = (uint2){hA01, hA23};
            *(uint2*)&TB[(q * 4 + r) * WS + nl * 4] = (uint2){hB01, hB23};
        }

        // ---- issue next pair's gathers (overlap layers 2-3) ----
        uint4 fyA2 = ((const uint4*)(xhf + ((size_t)((tA2 >> 15) * NN + nA2)) * OUT_DIM))[q];
        uint4 fyB2 = ((const uint4*)(xhf + ((size_t)((tB2 >> 15) * NN + nB2)) * OUT_DIM))[q];
        uint2 paA2, paB2;
        if (q == 0) {
            float2 ip, op;
            ip = ((const float2*)igrid)[nA2]; op = ((const float2*)ogrid)[tA2 & (NN - 1)];
            paA2.x = cvt2u(ip.x, ip.y); paA2.y = cvt2u(op.x, op.y);
            ip = ((const float2*)igrid)[nB2]; op = ((const float2*)ogrid)[tB2 & (NN - 1)];
            paB2.x = cvt2u(ip.x, ip.y); paB2.y = cvt2u(op.x, op.y);
        }
        f16 xA0n = xhf[(size_t)tA2 * OUT_DIM + nl],  xA1n = xhf[(size_t)tA2 * OUT_DIM + 16 + nl];
        f16 xB0n = xhf[(size_t)tB2 * OUT_DIM + nl],  xB1n = xhf[(size_t)tB2 * OUT_DIM + 16 + nl];

        // ---- layer 2 ----
        f16x8 bA0 = *(const f16x8*)&TA[nl * WS + q * 8];
        f16x8 bA1 = *(const f16x8*)&TA[nl * WS + 32 + q * 8];
        f16x8 bB0 = *(const f16x8*)&TB[nl * WS + q * 8];
        f16x8 bB1 = *(const f16x8*)&TB[nl * WS + 32 + q * 8];
        #pragma unroll
        for (int nb = 0; nb < 4; nb++) {
            f16x8 W0 = WFRAG(8 + nb);
            cA[nb] = __builtin_amdgcn_mfma_f32_16x16x32_f16(bA0, W0, zq, 0, 0, 0);
            cB[nb] = __builtin_amdgcn_mfma_f32_16x16x32_f16(bB0, W0, zq, 0, 0, 0);
        }
        #pragma unroll
        for (int nb = 0; nb < 4; nb++) {
            f16x8 W1 = WFRAG(12 + nb);
            cA[nb] = __builtin_amdgcn_mfma_f32_16x16x32_f16(bA1, W1, cA[nb], 0, 0, 0);
            cB[nb] = __builtin_amdgcn_mfma_f32_16x16x32_f16(bB1, W1, cB[nb], 0, 0, 0);
        }
        #pragma unroll
        for (int r = 0; r < 4; r++) {
            unsigned hA01 = gelu2bu(cA[0][r], cA[1][r], b2q0, gk);
            unsigned hA23 = gelu2bu(cA[2][r], cA[3][r], b2q1, gk);
            unsigned hB01 = gelu2bu(cB[0][r], cB[1][r], b2q0, gk);
            unsigned hB23 = gelu2bu(cB[2][r], cB[3][r], b2q1, gk);
            *(uint2*)&TA[(q * 4 + r) * WS + nl * 4] = (uint2){hA01, hA23};
            *(uint2*)&TB[(q * 4 + r) * WS + nl * 4] = (uint2){hB01, hB23};
        }

        // ---- layer 3 (w3 pre-scaled by 1/16) ----
        bA0 = *(const f16x8*)&TA[nl * WS + q * 8];
        bA1 = *(const f16x8*)&TA[nl * WS + 32 + q * 8];
        bB0 = *(const f16x8*)&TB[nl * WS + q * 8];
        bB1 = *(const f16x8*)&TB[nl * WS + 32 + q * 8];
        f32x4 dA[2], dB[2];
        #pragma unroll
        for (int nb = 0; nb < 2; nb++) {
            f16x8 W0 = WFRAG(16 + nb);
            dA[nb] = __builtin_amdgcn_mfma_f32_16x16x32_f16(bA0, W0, zq, 0, 0, 0);
            dB[nb] = __builtin_amdgcn_mfma_f32_16x16x32_f16(bB0, W0, zq, 0, 0, 0);
        }
        #pragma unroll
        for (int nb = 0; nb < 2; nb++) {
            f16x8 W1 = WFRAG(18 + nb);
            dA[nb] = __builtin_amdgcn_mfma_f32_16x16x32_f16(bA1, W1, dA[nb], 0, 0, 0);
            dB[nb] = __builtin_amdgcn_mfma_f32_16x16x32_f16(bB1, W1, dB[nb], 0, 0, 0);
        }

        // ---- epilogues: edge-mean (pre-scaled) + bias + residual, LN over 32 ----
        {
            float s0 = dA[0][0] + dA[0][1] + dA[0][2] + dA[0][3];
            float s1 = dA[1][0] + dA[1][1] + dA[1][2] + dA[1][3];
            float u0 = dB[0][0] + dB[0][1] + dB[0][2] + dB[0][3];
            float u1 = dB[1][0] + dB[1][1] + dB[1][2] + dB[1][3];
            s0 += __shfl_xor(s0, 16, 64); s0 += __shfl_xor(s0, 32, 64);
            s1 += __shfl_xor(s1, 16, 64); s1 += __shfl_xor(s1, 32, 64);
            u0 += __shfl_xor(u0, 16, 64); u0 += __shfl_xor(u0, 32, 64);
            u1 += __shfl_xor(u1, 16, 64); u1 += __shfl_xor(u1, 32, 64);

            float oA0 = s0 + b3v[0] + rA0;
            float oA1 = s1 + b3v[1] + rA1;
            float oB0 = u0 + b3v[0] + rB0;
            float oB1 = u1 + b3v[1] + rB1;

            float mA = rowsum16(oA0 + oA1) * (1.0f / 32.0f);
            float mB = rowsum16(oB0 + oB1) * (1.0f / 32.0f);
            float dA0 = oA0 - mA, dA1 = oA1 - mA, dB0 = oB0 - mB, dB1 = oB1 - mB;
            float vA = rowsum16(dA0 * dA0 + dA1 * dA1) * (1.0f / 32.0f);
            float vB = rowsum16(dB0 * dB0 + dB1 * dB1) * (1.0f / 32.0f);
            float rsA = rsqrtf(vA + 1e-5f);
            float rsB = rsqrtf(vB + 1e-5f);

            if (q == 0) {
                float* oa = out + (size_t)tA * OUT_DIM;
                float* ob = out + (size_t)tB * OUT_DIM;
                oa[nl]      = fmaf(dA0 * rsA, g0, be0);
                oa[16 + nl] = fmaf(dA1 * rsA, g1, be1);
                ob[nl]      = fmaf(dB0 * rsB, g0, be0);
                ob[16 + nl] = fmaf(dB1 * rsB, g1, be1);
            }
        }

        // ---- rotate prefetch state ----
        tA = tA2; tB = tB2;
        fyA = fyA2; fyB = fyB2;
        paA = paA2; paB = paB2;
        xA0 = xA0n; xA1 = xA1n; xB0 = xB0n; xB1 = xB1n;
    }
    #undef WFRAG
}

extern "C" void kernel_launch(void* const* d_in, const int* in_sizes, int n_in,
                              void* d_out, int out_size, void* d_ws, size_t ws_size,
                              hipStream_t stream) {
    const float* inp   = (const float*)d_in[0];
    const float* igrid = (const float*)d_in[1];
    const float* ogrid = (const float*)d_in[2];
    const int*   nbi   = (const int*)d_in[3];
    const float* Wp1   = (const float*)d_in[4];
    const float* bp1   = (const float*)d_in[5];
    const float* Wp2   = (const float*)d_in[6];
    const float* bp2   = (const float*)d_in[7];
    const float* Wk1   = (const float*)d_in[8];
    const float* bk1   = (const float*)d_in[9];
    const float* Wk2   = (const float*)d_in[10];
    const float* bk2   = (const float*)d_in[11];
    const float* Wk3   = (const float*)d_in[12];
    const float* bk3   = (const float*)d_in[13];
    const float* gma   = (const float*)d_in[14];
    const float* bta   = (const float*)d_in[15];
    float* out = (float*)d_out;
    f16* xhf = (f16*)d_ws;   // B*N*32 f16 = 8 MB

    point_mlp_kernel<<<1024, 256, 0, stream>>>(inp, Wp1, bp1, Wp2, bp2, xhf);
    gnn_edge_kernel<<<1024, 256, 0, stream>>>(xhf, igrid, ogrid, nbi,
                                              Wk1, bk1, Wk2, bk2, Wk3, bk3,
                                              gma, bta, out);
}

// Round 9
// 208.508 us; speedup vs baseline: 1.0448x; 1.0083x over previous
//
#include <hip/hip_runtime.h>

#define BB 4
#define NN 32768
#define KKN 16          // neighbors per node
#define IN_DIM 32
#define HID 64
#define OUT_DIM 32
#define KH 64
#define WS 72           // LDS row stride in f16 elems (144 B; reads 2-way=free)
#define TOT (BB * NN)   // 131072 = 2^17
#define NWAVES 4096     // grid 1024 blocks x 4 waves

typedef _Float16 f16;
typedef f16 f16x2 __attribute__((ext_vector_type(2)));
typedef f16 f16x4 __attribute__((ext_vector_type(4)));
typedef f16 f16x8 __attribute__((ext_vector_type(8)));
typedef float f32x4 __attribute__((ext_vector_type(4)));
typedef __fp16 hf16x2 __attribute__((ext_vector_type(2)));   // builtin's native type
typedef unsigned int u32x4 __attribute__((ext_vector_type(4)));

#define H2(c) ((f16x2){(f16)(c), (f16)(c)})
#define U2(c) (__builtin_bit_cast(unsigned, H2(c)))

// packed f32->f16x2 convert (v_cvt_pkrtz_f16_f32) -> raw u32 of 2 f16
__device__ __forceinline__ unsigned cvt2u(float a, float b) {
    hf16x2 r = __builtin_amdgcn_cvt_pkrtz(a, b);
    return __builtin_bit_cast(unsigned, r);
}
__device__ __forceinline__ f16x2 cvt2(float a, float b) {
    hf16x2 r = __builtin_amdgcn_cvt_pkrtz(a, b);
    return __builtin_bit_cast(f16x2, r);
}

// ---- single-instruction packed-f16 ops (VOP3P) ----
__device__ __forceinline__ unsigned pk_fma(unsigned a, unsigned b, unsigned c) {
    unsigned d;
    asm("v_pk_fma_f16 %0, %1, %2, %3" : "=v"(d) : "v"(a), "v"(b), "v"(c));
    return d;
}
__device__ __forceinline__ unsigned pk_mul(unsigned a, unsigned b) {
    unsigned d;
    asm("v_pk_mul_f16 %0, %1, %2" : "=v"(d) : "v"(a), "v"(b));
    return d;
}
__device__ __forceinline__ unsigned pk_add(unsigned a, unsigned b) {
    unsigned d;
    asm("v_pk_add_f16 %0, %1, %2" : "=v"(d) : "v"(a), "v"(b));
    return d;
}
__device__ __forceinline__ unsigned pk_max(unsigned a, unsigned b) {
    unsigned d;
    asm("v_pk_max_f16 %0, %1, %2" : "=v"(d) : "v"(a), "v"(b));
    return d;
}
__device__ __forceinline__ unsigned pk_min(unsigned a, unsigned b) {
    unsigned d;
    asm("v_pk_min_f16 %0, %1, %2" : "=v"(d) : "v"(a), "v"(b));
    return d;
}

struct GeluK {
    unsigned n35, p35, q4, c5, c4, c3, c2, c1, c0, half;
};
__device__ __forceinline__ GeluK gelu_consts() {
    GeluK k;
    k.n35  = U2(-3.5f);        k.p35 = U2(3.5f);
    k.q4   = U2(0.25f);        k.half = U2(0.5f);
    k.c5   = U2(-1.0110344f);  k.c4 = U2(2.85016064f);
    k.c3   = U2(-3.40439040f); k.c2 = U2(2.32402432f);
    k.c1   = U2(-1.04974080f); k.c0 = U2(0.39879504f);
    return k;
}

// packed-f16 polynomial gelu on 2 values in one u32.
__device__ __forceinline__ unsigned gelu2u(unsigned x, const GeluK& k) {
    unsigned s  = pk_min(pk_max(x, k.n35), k.p35);
    unsigned s4 = pk_mul(s, k.q4);
    unsigned t  = pk_mul(s4, s4);
    unsigned g  = pk_fma(k.c5, t, k.c4);
    g = pk_fma(g, t, k.c3);
    g = pk_fma(g, t, k.c2);
    g = pk_fma(g, t, k.c1);
    g = pk_fma(g, t, k.c0);
    unsigned h  = pk_fma(s, g, k.half);
    return pk_mul(x, h);
}
__device__ __forceinline__ unsigned gelu2bu(float a, float b, unsigned bias, const GeluK& k) {
    return gelu2u(pk_add(cvt2u(a, b), bias), k);
}

// DPP add: v += lane-permuted v (within 16-lane row).
template <int CTRL>
__device__ __forceinline__ float dppadd(float v) {
    union { float f; int i; } u, r;
    u.f = v;
    r.i = __builtin_amdgcn_update_dpp(0, u.i, CTRL, 0xf, 0xf, true);
    return v + r.f;
}
__device__ __forceinline__ float rowsum16(float v) {
    v = dppadd<0xB1>(v);    // quad xor 1
    v = dppadd<0x4E>(v);    // quad xor 2
    v = dppadd<0x124>(v);   // row rotate 4
    v = dppadd<0x128>(v);   // row rotate 8
    return v;
}

// ---------------- Kernel A: point MLP via MFMA (persistent) ----------------
__global__ __launch_bounds__(256) void point_mlp_kernel(
    const float* __restrict__ inp, const float* __restrict__ Wp1,
    const float* __restrict__ bp1, const float* __restrict__ Wp2,
    const float* __restrict__ bp2, f16* __restrict__ xhf)
{
    __shared__ __align__(16) f16 hb[4][16 * WS];
    const int tid = threadIdx.x, w = tid >> 6, lane = tid & 63;
    const int q = lane >> 4, nl = lane & 15;
    const GeluK gk = gelu_consts();

    f16x8 w1f[4];
    #pragma unroll
    for (int nb = 0; nb < 4; nb++)
        #pragma unroll
        for (int j = 0; j < 8; j++)
            w1f[nb][j] = (f16)Wp1[(q * 8 + j) * HID + nb * 16 + nl];
    f16x8 w2f[2][2];        // rows pre-permuted by p_inv(k) = (k&3)*16 + k/4
    #pragma unroll
    for (int nb = 0; nb < 2; nb++)
        #pragma unroll
        for (int c = 0; c < 2; c++)
            #pragma unroll
            for (int j = 0; j < 8; j++) {
                int k = c * 32 + q * 8 + j, kp = ((k & 3) << 4) | (k >> 2);
                w2f[nb][c][j] = (f16)Wp2[kp * OUT_DIM + nb * 16 + nl];
            }
    const unsigned b1q0 = cvt2u(bp1[nl],      bp1[16 + nl]);
    const unsigned b1q1 = cvt2u(bp1[32 + nl], bp1[48 + nl]);
    float b2v[2];
    b2v[0] = bp2[nl]; b2v[1] = bp2[16 + nl];
    const f32x4 zq = (f32x4){0.f, 0.f, 0.f, 0.f};

    const int gw = blockIdx.x * 4 + w;
    const int nw = gridDim.x * 4;

    for (int t = gw; t < TOT / 16; t += nw) {
        const int R = t * 16;
        const float* ap = inp + (size_t)(R + nl) * IN_DIM + q * 8;
        float4 av0 = *(const float4*)ap, av1 = *(const float4*)(ap + 4);
        f16x2 p01 = cvt2(av0.x, av0.y);
        f16x2 p23 = cvt2(av0.z, av0.w);
        f16x2 p45 = cvt2(av1.x, av1.y);
        f16x2 p67 = cvt2(av1.z, av1.w);
        f16x8 af = (f16x8){p01.x, p01.y, p23.x, p23.y, p45.x, p45.y, p67.x, p67.y};

        f32x4 acc[4];
        #pragma unroll
        for (int nb = 0; nb < 4; nb++)
            acc[nb] = __builtin_amdgcn_mfma_f32_16x16x32_f16(af, w1f[nb], zq, 0, 0, 0);

        #pragma unroll
        for (int r = 0; r < 4; r++) {
            unsigned h01 = gelu2bu(acc[0][r], acc[1][r], b1q0, gk);
            unsigned h23 = gelu2bu(acc[2][r], acc[3][r], b1q1, gk);
            *(uint2*)&hb[w][(q * 4 + r) * WS + nl * 4] = (uint2){h01, h23};
        }
        f16x8 a0 = *(const f16x8*)&hb[w][nl * WS + q * 8];
        f16x8 a1 = *(const f16x8*)&hb[w][nl * WS + 32 + q * 8];
        f32x4 a2[2];
        #pragma unroll
        for (int nb = 0; nb < 2; nb++) {
            a2[nb] = (f32x4){b2v[nb], b2v[nb], b2v[nb], b2v[nb]};
            a2[nb] = __builtin_amdgcn_mfma_f32_16x16x32_f16(a0, w2f[nb][0], a2[nb], 0, 0, 0);
            a2[nb] = __builtin_amdgcn_mfma_f32_16x16x32_f16(a1, w2f[nb][1], a2[nb], 0, 0, 0);
        }
        #pragma unroll
        for (int r = 0; r < 4; r++)
            #pragma unroll
            for (int nb = 0; nb < 2; nb++)
                xhf[(size_t)(R + q * 4 + r) * OUT_DIM + nb * 16 + nl] = (f16)a2[nb][r];
    }
}

// ---------------- Kernel B: edge MLP, 2 nodes/iter, weights in LDS ----------------
// R9: R8 structure + __launch_bounds__(256, 4).
// Register model (calibrated R2/R3-R7/R8): unified VGPR+AGPR file is the
// occupancy cap; arch-VGPR counter hides ~96 AGPRs -> all prior rounds ran
// 2 waves/SIMD (occ ~20-26%) and were latency-starved. R8 moved the 80-reg
// weight set to LDS, so live demand is now ~115 regs: forcing the 128-reg
// (4 waves/EU) budget should fit WITHOUT the R2 spill catastrophe.
// Spill tripwire: WRITE_SIZE must stay 16 MB.
__global__ __launch_bounds__(256, 4) void gnn_edge_kernel(
    const f16*   __restrict__ xhf,
    const float* __restrict__ igrid, const float* __restrict__ ogrid,
    const int*   __restrict__ nbi,
    const float* __restrict__ Wk1, const float* __restrict__ bk1,
    const float* __restrict__ Wk2, const float* __restrict__ bk2,
    const float* __restrict__ Wk3, const float* __restrict__ bk3,
    const float* __restrict__ gma, const float* __restrict__ bta,
    float* __restrict__ out)
{
    __shared__ __align__(16) f16 tile[8][16 * WS];   // 2 h-tiles/wave, 18.4 KB
    __shared__ __align__(16) f16 wf[20][64][8];      // 20 B-frags, 20.5 KB

    const int tid = threadIdx.x, w = tid >> 6, lane = tid & 63;
    const int q = lane >> 4, nl = lane & 15;
    f16* __restrict__ TA = tile[w * 2];
    f16* __restrict__ TB = tile[w * 2 + 1];
    const GeluK gk = gelu_consts();

    // ---- build weight-frag table: wave w owns frags 5w..5w+4; each lane
    // writes its own 16 B (frag data depends only on lane) ----
    #pragma unroll 1
    for (int f = w * 5; f < w * 5 + 5; ++f) {
        f16x8 v;
        if (f < 4) {                     // w1[nb][0]
            int nb = f;
            #pragma unroll
            for (int j = 0; j < 8; j++)
                v[j] = (f16)Wk1[(4 + q * 8 + j) * KH + nb * 16 + nl];
        } else if (f < 8) {              // w1[nb][1] (pos rows; q==0, j<4 only)
            int nb = f - 4;
            #pragma unroll
            for (int j = 0; j < 8; j++) {
                float x = 0.0f;
                if (j < 4 && q == 0) x = Wk1[j * KH + nb * 16 + nl];
                v[j] = (f16)x;
            }
        } else if (f < 16) {             // w2[nb][c], c = (f-8)/4
            int nb = (f - 8) & 3, c = (f - 8) >> 2;
            #pragma unroll
            for (int j = 0; j < 8; j++) {
                int k = c * 32 + q * 8 + j, kp = ((k & 3) << 4) | (k >> 2);
                v[j] = (f16)Wk2[kp * KH + nb * 16 + nl];
            }
        } else {                         // w3[nb][c] pre-scaled by 1/16
            int nb = (f - 16) & 1, c = (f - 16) >> 1;
            #pragma unroll
            for (int j = 0; j < 8; j++) {
                int k = c * 32 + q * 8 + j, kp = ((k & 3) << 4) | (k >> 2);
                v[j] = (f16)(Wk3[kp * OUT_DIM + nb * 16 + nl] * 0.0625f);
            }
        }
        *(f16x8*)&wf[f][lane][0] = v;
    }
    __syncthreads();   // one-time: weight table ready
    #define WFRAG(f) (*(const f16x8*)&wf[(f)][lane][0])

    // packed-f16 bias pairs for gelu re-injection
    const unsigned b1q0 = cvt2u(bk1[nl],      bk1[16 + nl]);
    const unsigned b1q1 = cvt2u(bk1[32 + nl], bk1[48 + nl]);
    const unsigned b2q0 = cvt2u(bk2[nl],      bk2[16 + nl]);
    const unsigned b2q1 = cvt2u(bk2[32 + nl], bk2[48 + nl]);
    float b3v[2];
    b3v[0] = bk3[nl]; b3v[1] = bk3[16 + nl];
    const float g0 = gma[nl], g1 = gma[16 + nl], be0 = bta[nl], be1 = bta[16 + nl];

    const f32x4 zq = (f32x4){0.f, 0.f, 0.f, 0.f};

    const int gw = blockIdx.x * 4 + w;

    // ---- prologue prefetch (pair 0): gather lanes in A-frag order ----
    int tA = gw, tB = gw + NWAVES;
    int nA = nbi[(tA & (NN - 1)) * KKN + nl];
    int nB = nbi[(tB & (NN - 1)) * KKN + nl];
    uint4 fyA = ((const uint4*)(xhf + ((size_t)((tA >> 15) * NN + nA)) * OUT_DIM))[q];
    uint4 fyB = ((const uint4*)(xhf + ((size_t)((tB >> 15) * NN + nB)) * OUT_DIM))[q];
    uint2 paA, paB;
    if (q == 0) {
        float2 ip, op;
        ip = ((const float2*)igrid)[nA]; op = ((const float2*)ogrid)[tA & (NN - 1)];
        paA.x = cvt2u(ip.x, ip.y); paA.y = cvt2u(op.x, op.y);
        ip = ((const float2*)igrid)[nB]; op = ((const float2*)ogrid)[tB & (NN - 1)];
        paB.x = cvt2u(ip.x, ip.y); paB.y = cvt2u(op.x, op.y);
    }
    f16 xA0 = xhf[(size_t)tA * OUT_DIM + nl],      xA1 = xhf[(size_t)tA * OUT_DIM + 16 + nl];
    f16 xB0 = xhf[(size_t)tB * OUT_DIM + nl],      xB1 = xhf[(size_t)tB * OUT_DIM + 16 + nl];

    #pragma unroll 1
    for (int it = 0; it < TOT / (2 * NWAVES); ++it) {
        const float rA0 = (float)xA0, rA1 = (float)xA1, rB0 = (float)xB0, rB1 = (float)xB1;

        const int tA2 = (tA + 2 * NWAVES) & (TOT - 1);
        const int tB2 = tA2 + NWAVES;
        const int nA2 = nbi[(tA2 & (NN - 1)) * KKN + nl];
        const int nB2 = nbi[(tB2 & (NN - 1)) * KKN + nl];

        // ---- layer 1: A-operands straight from prefetched registers ----
        f16x8 aA0 = __builtin_bit_cast(f16x8, fyA);
        f16x8 aB0 = __builtin_bit_cast(f16x8, fyB);
        u32x4 uA1 = (u32x4){q == 0 ? paA.x : 0u, q == 0 ? paA.y : 0u, 0u, 0u};
        u32x4 uB1 = (u32x4){q == 0 ? paB.x : 0u, q == 0 ? paB.y : 0u, 0u, 0u};
        f16x8 aA1 = __builtin_bit_cast(f16x8, uA1);
        f16x8 aB1 = __builtin_bit_cast(f16x8, uB1);

        f32x4 cA[4], cB[4];
        #pragma unroll
        for (int nb = 0; nb < 4; nb++) {
            f16x8 W0 = WFRAG(nb);
            cA[nb] = __builtin_amdgcn_mfma_f32_16x16x32_f16(aA0, W0, zq, 0, 0, 0);
            cB[nb] = __builtin_amdgcn_mfma_f32_16x16x32_f16(aB0, W0, zq, 0, 0, 0);
        }
        #pragma unroll
        for (int nb = 0; nb < 4; nb++) {
            f16x8 W1 = WFRAG(4 + nb);
            cA[nb] = __builtin_amdgcn_mfma_f32_16x16x32_f16(aA1, W1, cA[nb], 0, 0, 0);
            cB[nb] = __builtin_amdgcn_mfma_f32_16x16x32_f16(aB1, W1, cB[nb], 0, 0, 0);
        }
        #pragma unroll
        for (int r = 0; r < 4; r++) {
            unsigned hA01 = gelu2bu(cA[0][r], cA[1][r], b1q0, gk);
            unsigned hA23 = gelu2bu(cA[2][r], cA[3][r], b1q1, gk);
            unsigned hB01 = gelu2bu(cB[0][r], cB[1][r], b1q0, gk);
            unsigned hB23 = gelu2bu(cB[2][r], cB[3][r], b1q1, gk);
            *(uint2*)&TA[(q * 4 + r) * WS + nl * 4] = (uint2){hA01, hA23};
            *(uint2*)&TB[(q * 4 + r) * WS + nl * 4] = (uint2){hB01, hB23};
        }

        // ---- issue next pair's gathers (overlap layers 2-3) ----
        uint4 fyA2 = ((const uint4*)(xhf + ((size_t)((tA2 >> 15) * NN + nA2)) * OUT_DIM))[q];
        uint4 fyB2 = ((const uint4*)(xhf + ((size_t)((tB2 >> 15) * NN + nB2)) * OUT_DIM))[q];
        uint2 paA2, paB2;
        if (q == 0) {
            float2 ip, op;
            ip = ((const float2*)igrid)[nA2]; op = ((const float2*)ogrid)[tA2 & (NN - 1)];
            paA2.x = cvt2u(ip.x, ip.y); paA2.y = cvt2u(op.x, op.y);
            ip = ((const float2*)igrid)[nB2]; op = ((const float2*)ogrid)[tB2 & (NN - 1)];
            paB2.x = cvt2u(ip.x, ip.y); paB2.y = cvt2u(op.x, op.y);
        }
        f16 xA0n = xhf[(size_t)tA2 * OUT_DIM + nl],  xA1n = xhf[(size_t)tA2 * OUT_DIM + 16 + nl];
        f16 xB0n = xhf[(size_t)tB2 * OUT_DIM + nl],  xB1n = xhf[(size_t)tB2 * OUT_DIM + 16 + nl];

        // ---- layer 2 ----
        f16x8 bA0 = *(const f16x8*)&TA[nl * WS + q * 8];
        f16x8 bA1 = *(const f16x8*)&TA[nl * WS + 32 + q * 8];
        f16x8 bB0 = *(const f16x8*)&TB[nl * WS + q * 8];
        f16x8 bB1 = *(const f16x8*)&TB[nl * WS + 32 + q * 8];
        #pragma unroll
        for (int nb = 0; nb < 4; nb++) {
            f16x8 W0 = WFRAG(8 + nb);
            cA[nb] = __builtin_amdgcn_mfma_f32_16x16x32_f16(bA0, W0, zq, 0, 0, 0);
            cB[nb] = __builtin_amdgcn_mfma_f32_16x16x32_f16(bB0, W0, zq, 0, 0, 0);
        }
        #pragma unroll
        for (int nb = 0; nb < 4; nb++) {
            f16x8 W1 = WFRAG(12 + nb);
            cA[nb] = __builtin_amdgcn_mfma_f32_16x16x32_f16(bA1, W1, cA[nb], 0, 0, 0);
            cB[nb] = __builtin_amdgcn_mfma_f32_16x16x32_f16(bB1, W1, cB[nb], 0, 0, 0);
        }
        #pragma unroll
        for (int r = 0; r < 4; r++) {
            unsigned hA01 = gelu2bu(cA[0][r], cA[1][r], b2q0, gk);
            unsigned hA23 = gelu2bu(cA[2][r], cA[3][r], b2q1, gk);
            unsigned hB01 = gelu2bu(cB[0][r], cB[1][r], b2q0, gk);
            unsigned hB23 = gelu2bu(cB[2][r], cB[3][r], b2q1, gk);
            *(uint2*)&TA[(q * 4 + r) * WS + nl * 4] = (uint2){hA01, hA23};
            *(uint2*)&TB[(q * 4 + r) * WS + nl * 4] = (uint2){hB01, hB23};
        }

        // ---- layer 3 (w3 pre-scaled by 1/16) ----
        bA0 = *(const f16x8*)&TA[nl * WS + q * 8];
        bA1 = *(const f16x8*)&TA[nl * WS + 32 + q * 8];
        bB0 = *(const f16x8*)&TB[nl * WS + q * 8];
        bB1 = *(const f16x8*)&TB[nl * WS + 32 + q * 8];
        f32x4 dA[2], dB[2];
        #pragma unroll
        for (int nb = 0; nb < 2; nb++) {
            f16x8 W0 = WFRAG(16 + nb);
            dA[nb] = __builtin_amdgcn_mfma_f32_16x16x32_f16(bA0, W0, zq, 0, 0, 0);
            dB[nb] = __builtin_amdgcn_mfma_f32_16x16x32_f16(bB0, W0, zq, 0, 0, 0);
        }
        #pragma unroll
        for (int nb = 0; nb < 2; nb++) {
            f16x8 W1 = WFRAG(18 + nb);
            dA[nb] = __builtin_amdgcn_mfma_f32_16x16x32_f16(bA1, W1, dA[nb], 0, 0, 0);
            dB[nb] = __builtin_amdgcn_mfma_f32_16x16x32_f16(bB1, W1, dB[nb], 0, 0, 0);
        }

        // ---- epilogues: edge-mean (pre-scaled) + bias + residual, LN over 32 ----
        {
            float s0 = dA[0][0] + dA[0][1] + dA[0][2] + dA[0][3];
            float s1 = dA[1][0] + dA[1][1] + dA[1][2] + dA[1][3];
            float u0 = dB[0][0] + dB[0][1] + dB[0][2] + dB[0][3];
            float u1 = dB[1][0] + dB[1][1] + dB[1][2] + dB[1][3];
            s0 += __shfl_xor(s0, 16, 64); s0 += __shfl_xor(s0, 32, 64);
            s1 += __shfl_xor(s1, 16, 64); s1 += __shfl_xor(s1, 32, 64);
            u0 += __shfl_xor(u0, 16, 64); u0 += __shfl_xor(u0, 32, 64);
            u1 += __shfl_xor(u1, 16, 64); u1 += __shfl_xor(u1, 32, 64);

            float oA0 = s0 + b3v[0] + rA0;
            float oA1 = s1 + b3v[1] + rA1;
            float oB0 = u0 + b3v[0] + rB0;
            float oB1 = u1 + b3v[1] + rB1;

            float mA = rowsum16(oA0 + oA1) * (1.0f / 32.0f);
            float mB = rowsum16(oB0 + oB1) * (1.0f / 32.0f);
            float dA0 = oA0 - mA, dA1 = oA1 - mA, dB0 = oB0 - mB, dB1 = oB1 - mB;
            float vA = rowsum16(dA0 * dA0 + dA1 * dA1) * (1.0f / 32.0f);
            float vB = rowsum16(dB0 * dB0 + dB1 * dB1) * (1.0f / 32.0f);
            float rsA = rsqrtf(vA + 1e-5f);
            float rsB = rsqrtf(vB + 1e-5f);

            if (q == 0) {
                float* oa = out + (size_t)tA * OUT_DIM;
                float* ob = out + (size_t)tB * OUT_DIM;
                oa[nl]      = fmaf(dA0 * rsA, g0, be0);
                oa[16 + nl] = fmaf(dA1 * rsA, g1, be1);
                ob[nl]      = fmaf(dB0 * rsB, g0, be0);
                ob[16 + nl] = fmaf(dB1 * rsB, g1, be1);
            }
        }

        // ---- rotate prefetch state ----
        tA = tA2; tB = tB2;
        fyA = fyA2; fyB = fyB2;
        paA = paA2; paB = paB2;
        xA0 = xA0n; xA1 = xA1n; xB0 = xB0n; xB1 = xB1n;
    }
    #undef WFRAG
}

extern "C" void kernel_launch(void* const* d_in, const int* in_sizes, int n_in,
                              void* d_out, int out_size, void* d_ws, size_t ws_size,
                              hipStream_t stream) {
    const float* inp   = (const float*)d_in[0];
    const float* igrid = (const float*)d_in[1];
    const float* ogrid = (const float*)d_in[2];
    const int*   nbi   = (const int*)d_in[3];
    const float* Wp1   = (const float*)d_in[4];
    const float* bp1   = (const float*)d_in[5];
    const float* Wp2   = (const float*)d_in[6];
    const float* bp2   = (const float*)d_in[7];
    const float* Wk1   = (const float*)d_in[8];
    const float* bk1   = (const float*)d_in[9];
    const float* Wk2   = (const float*)d_in[10];
    const float* bk2   = (const float*)d_in[11];
    const float* Wk3   = (const float*)d_in[12];
    const float* bk3   = (const float*)d_in[13];
    const float* gma   = (const float*)d_in[14];
    const float* bta   = (const float*)d_in[15];
    float* out = (float*)d_out;
    f16* xhf = (f16*)d_ws;   // B*N*32 f16 = 8 MB

    point_mlp_kernel<<<1024, 256, 0, stream>>>(inp, Wp1, bp1, Wp2, bp2, xhf);
    gnn_edge_kernel<<<1024, 256, 0, stream>>>(xhf, igrid, ogrid, nbi,
                                              Wk1, bk1, Wk2, bk2, Wk3, bk3,
                                              gma, bta, out);
}

// Round 10
// 202.182 us; speedup vs baseline: 1.0775x; 1.0313x over previous
//
#include <hip/hip_runtime.h>

#define BB 4
#define NN 32768
#define KKN 16          // neighbors per node
#define IN_DIM 32
#define HID 64
#define OUT_DIM 32
#define KH 64
#define WS 72           // LDS row stride in f16 elems (144 B; reads 2-way=free)
#define TOT (BB * NN)   // 131072 = 2^17
#define NWAVES 4096     // grid 1024 blocks x 4 waves

typedef _Float16 f16;
typedef f16 f16x2 __attribute__((ext_vector_type(2)));
typedef f16 f16x4 __attribute__((ext_vector_type(4)));
typedef f16 f16x8 __attribute__((ext_vector_type(8)));
typedef float f32x4 __attribute__((ext_vector_type(4)));
typedef __fp16 hf16x2 __attribute__((ext_vector_type(2)));   // builtin's native type
typedef unsigned int u32x4 __attribute__((ext_vector_type(4)));

#define H2(c) ((f16x2){(f16)(c), (f16)(c)})
#define U2(c) (__builtin_bit_cast(unsigned, H2(c)))

// packed f32->f16x2 convert (v_cvt_pkrtz_f16_f32) -> raw u32 of 2 f16
__device__ __forceinline__ unsigned cvt2u(float a, float b) {
    hf16x2 r = __builtin_amdgcn_cvt_pkrtz(a, b);
    return __builtin_bit_cast(unsigned, r);
}
__device__ __forceinline__ f16x2 cvt2(float a, float b) {
    hf16x2 r = __builtin_amdgcn_cvt_pkrtz(a, b);
    return __builtin_bit_cast(f16x2, r);
}

// ---- single-instruction packed-f16 ops (VOP3P) ----
__device__ __forceinline__ unsigned pk_fma(unsigned a, unsigned b, unsigned c) {
    unsigned d;
    asm("v_pk_fma_f16 %0, %1, %2, %3" : "=v"(d) : "v"(a), "v"(b), "v"(c));
    return d;
}
__device__ __forceinline__ unsigned pk_mul(unsigned a, unsigned b) {
    unsigned d;
    asm("v_pk_mul_f16 %0, %1, %2" : "=v"(d) : "v"(a), "v"(b));
    return d;
}
__device__ __forceinline__ unsigned pk_add(unsigned a, unsigned b) {
    unsigned d;
    asm("v_pk_add_f16 %0, %1, %2" : "=v"(d) : "v"(a), "v"(b));
    return d;
}
__device__ __forceinline__ unsigned pk_max(unsigned a, unsigned b) {
    unsigned d;
    asm("v_pk_max_f16 %0, %1, %2" : "=v"(d) : "v"(a), "v"(b));
    return d;
}
__device__ __forceinline__ unsigned pk_min(unsigned a, unsigned b) {
    unsigned d;
    asm("v_pk_min_f16 %0, %1, %2" : "=v"(d) : "v"(a), "v"(b));
    return d;
}

struct GeluK {
    unsigned n35, p35, q4, c5, c4, c3, c2, c1, c0, half;
};
__device__ __forceinline__ GeluK gelu_consts() {
    GeluK k;
    k.n35  = U2(-3.5f);        k.p35 = U2(3.5f);
    k.q4   = U2(0.25f);        k.half = U2(0.5f);
    k.c5   = U2(-1.0110344f);  k.c4 = U2(2.85016064f);
    k.c3   = U2(-3.40439040f); k.c2 = U2(2.32402432f);
    k.c1   = U2(-1.04974080f); k.c0 = U2(0.39879504f);
    return k;
}

// packed-f16 polynomial gelu on 2 values in one u32.
__device__ __forceinline__ unsigned gelu2u(unsigned x, const GeluK& k) {
    unsigned s  = pk_min(pk_max(x, k.n35), k.p35);
    unsigned s4 = pk_mul(s, k.q4);
    unsigned t  = pk_mul(s4, s4);
    unsigned g  = pk_fma(k.c5, t, k.c4);
    g = pk_fma(g, t, k.c3);
    g = pk_fma(g, t, k.c2);
    g = pk_fma(g, t, k.c1);
    g = pk_fma(g, t, k.c0);
    unsigned h  = pk_fma(s, g, k.half);
    return pk_mul(x, h);
}
__device__ __forceinline__ unsigned gelu2bu(float a, float b, unsigned bias, const GeluK& k) {
    return gelu2u(pk_add(cvt2u(a, b), bias), k);
}

// DPP add: v += lane-permuted v (within 16-lane row).
template <int CTRL>
__device__ __forceinline__ float dppadd(float v) {
    union { float f; int i; } u, r;
    u.f = v;
    r.i = __builtin_amdgcn_update_dpp(0, u.i, CTRL, 0xf, 0xf, true);
    return v + r.f;
}
__device__ __forceinline__ float rowsum16(float v) {
    v = dppadd<0xB1>(v);    // quad xor 1
    v = dppadd<0x4E>(v);    // quad xor 2
    v = dppadd<0x124>(v);   // row rotate 4
    v = dppadd<0x128>(v);   // row rotate 8
    return v;
}

// ---------------- Kernel A: point MLP via MFMA (persistent) ----------------
__global__ __launch_bounds__(256) void point_mlp_kernel(
    const float* __restrict__ inp, const float* __restrict__ Wp1,
    const float* __restrict__ bp1, const float* __restrict__ Wp2,
    const float* __restrict__ bp2, f16* __restrict__ xhf)
{
    __shared__ __align__(16) f16 hb[4][16 * WS];
    const int tid = threadIdx.x, w = tid >> 6, lane = tid & 63;
    const int q = lane >> 4, nl = lane & 15;
    const GeluK gk = gelu_consts();

    f16x8 w1f[4];
    #pragma unroll
    for (int nb = 0; nb < 4; nb++)
        #pragma unroll
        for (int j = 0; j < 8; j++)
            w1f[nb][j] = (f16)Wp1[(q * 8 + j) * HID + nb * 16 + nl];
    f16x8 w2f[2][2];        // rows pre-permuted by p_inv(k) = (k&3)*16 + k/4
    #pragma unroll
    for (int nb = 0; nb < 2; nb++)
        #pragma unroll
        for (int c = 0; c < 2; c++)
            #pragma unroll
            for (int j = 0; j < 8; j++) {
                int k = c * 32 + q * 8 + j, kp = ((k & 3) << 4) | (k >> 2);
                w2f[nb][c][j] = (f16)Wp2[kp * OUT_DIM + nb * 16 + nl];
            }
    const unsigned b1q0 = cvt2u(bp1[nl],      bp1[16 + nl]);
    const unsigned b1q1 = cvt2u(bp1[32 + nl], bp1[48 + nl]);
    float b2v[2];
    b2v[0] = bp2[nl]; b2v[1] = bp2[16 + nl];
    const f32x4 zq = (f32x4){0.f, 0.f, 0.f, 0.f};

    const int gw = blockIdx.x * 4 + w;
    const int nw = gridDim.x * 4;

    for (int t = gw; t < TOT / 16; t += nw) {
        const int R = t * 16;
        const float* ap = inp + (size_t)(R + nl) * IN_DIM + q * 8;
        float4 av0 = *(const float4*)ap, av1 = *(const float4*)(ap + 4);
        f16x2 p01 = cvt2(av0.x, av0.y);
        f16x2 p23 = cvt2(av0.z, av0.w);
        f16x2 p45 = cvt2(av1.x, av1.y);
        f16x2 p67 = cvt2(av1.z, av1.w);
        f16x8 af = (f16x8){p01.x, p01.y, p23.x, p23.y, p45.x, p45.y, p67.x, p67.y};

        f32x4 acc[4];
        #pragma unroll
        for (int nb = 0; nb < 4; nb++)
            acc[nb] = __builtin_amdgcn_mfma_f32_16x16x32_f16(af, w1f[nb], zq, 0, 0, 0);

        #pragma unroll
        for (int r = 0; r < 4; r++) {
            unsigned h01 = gelu2bu(acc[0][r], acc[1][r], b1q0, gk);
            unsigned h23 = gelu2bu(acc[2][r], acc[3][r], b1q1, gk);
            *(uint2*)&hb[w][(q * 4 + r) * WS + nl * 4] = (uint2){h01, h23};
        }
        f16x8 a0 = *(const f16x8*)&hb[w][nl * WS + q * 8];
        f16x8 a1 = *(const f16x8*)&hb[w][nl * WS + 32 + q * 8];
        f32x4 a2[2];
        #pragma unroll
        for (int nb = 0; nb < 2; nb++) {
            a2[nb] = (f32x4){b2v[nb], b2v[nb], b2v[nb], b2v[nb]};
            a2[nb] = __builtin_amdgcn_mfma_f32_16x16x32_f16(a0, w2f[nb][0], a2[nb], 0, 0, 0);
            a2[nb] = __builtin_amdgcn_mfma_f32_16x16x32_f16(a1, w2f[nb][1], a2[nb], 0, 0, 0);
        }
        #pragma unroll
        for (int r = 0; r < 4; r++)
            #pragma unroll
            for (int nb = 0; nb < 2; nb++)
                xhf[(size_t)(R + q * 4 + r) * OUT_DIM + nb * 16 + nl] = (f16)a2[nb][r];
    }
}

// ---------------- Kernel B: edge MLP, 2 nodes/iter, weights in LDS ----------------
// R10: R8 structure + __launch_bounds__(256, 3).
// Register-model calibration across R2/R3-R8/R9: the unified VGPR+AGPR file
// caps occupancy; forcing 4 waves/EU (R9, 64 arch-VGPR) spilled (+25 MB
// FETCH/WRITE scratch traffic) yet still reached only ~3 waves/SIMD.
// (256,3) targets a 96-reg budget: fits the ~95-reg live state with NO
// spill while keeping the same 3-wave residency R9 actually achieved.
// Spill tripwire: WRITE_SIZE must be 16.4 MB (R9's 40.6 MB = spill).
__global__ __launch_bounds__(256, 3) void gnn_edge_kernel(
    const f16*   __restrict__ xhf,
    const float* __restrict__ igrid, const float* __restrict__ ogrid,
    const int*   __restrict__ nbi,
    const float* __restrict__ Wk1, const float* __restrict__ bk1,
    const float* __restrict__ Wk2, const float* __restrict__ bk2,
    const float* __restrict__ Wk3, const float* __restrict__ bk3,
    const float* __restrict__ gma, const float* __restrict__ bta,
    float* __restrict__ out)
{
    __shared__ __align__(16) f16 tile[8][16 * WS];   // 2 h-tiles/wave, 18.4 KB
    __shared__ __align__(16) f16 wf[20][64][8];      // 20 B-frags, 20.5 KB

    const int tid = threadIdx.x, w = tid >> 6, lane = tid & 63;
    const int q = lane >> 4, nl = lane & 15;
    f16* __restrict__ TA = tile[w * 2];
    f16* __restrict__ TB = tile[w * 2 + 1];
    const GeluK gk = gelu_consts();

    // ---- build weight-frag table: wave w owns frags 5w..5w+4; each lane
    // writes its own 16 B (frag data depends only on lane) ----
    #pragma unroll 1
    for (int f = w * 5; f < w * 5 + 5; ++f) {
        f16x8 v;
        if (f < 4) {                     // w1[nb][0]
            int nb = f;
            #pragma unroll
            for (int j = 0; j < 8; j++)
                v[j] = (f16)Wk1[(4 + q * 8 + j) * KH + nb * 16 + nl];
        } else if (f < 8) {              // w1[nb][1] (pos rows; q==0, j<4 only)
            int nb = f - 4;
            #pragma unroll
            for (int j = 0; j < 8; j++) {
                float x = 0.0f;
                if (j < 4 && q == 0) x = Wk1[j * KH + nb * 16 + nl];
                v[j] = (f16)x;
            }
        } else if (f < 16) {             // w2[nb][c], c = (f-8)/4
            int nb = (f - 8) & 3, c = (f - 8) >> 2;
            #pragma unroll
            for (int j = 0; j < 8; j++) {
                int k = c * 32 + q * 8 + j, kp = ((k & 3) << 4) | (k >> 2);
                v[j] = (f16)Wk2[kp * KH + nb * 16 + nl];
            }
        } else {                         // w3[nb][c] pre-scaled by 1/16
            int nb = (f - 16) & 1, c = (f - 16) >> 1;
            #pragma unroll
            for (int j = 0; j < 8; j++) {
                int k = c * 32 + q * 8 + j, kp = ((k & 3) << 4) | (k >> 2);
                v[j] = (f16)(Wk3[kp * OUT_DIM + nb * 16 + nl] * 0.0625f);
            }
        }
        *(f16x8*)&wf[f][lane][0] = v;
    }
    __syncthreads();   // one-time: weight table ready
    #define WFRAG(f) (*(const f16x8*)&wf[(f)][lane][0])

    // packed-f16 bias pairs for gelu re-injection
    const unsigned b1q0 = cvt2u(bk1[nl],      bk1[16 + nl]);
    const unsigned b1q1 = cvt2u(bk1[32 + nl], bk1[48 + nl]);
    const unsigned b2q0 = cvt2u(bk2[nl],      bk2[16 + nl]);
    const unsigned b2q1 = cvt2u(bk2[32 + nl], bk2[48 + nl]);
    float b3v[2];
    b3v[0] = bk3[nl]; b3v[1] = bk3[16 + nl];
    const float g0 = gma[nl], g1 = gma[16 + nl], be0 = bta[nl], be1 = bta[16 + nl];

    const f32x4 zq = (f32x4){0.f, 0.f, 0.f, 0.f};

    const int gw = blockIdx.x * 4 + w;

    // ---- prologue prefetch (pair 0): gather lanes in A-frag order ----
    int tA = gw, tB = gw + NWAVES;
    int nA = nbi[(tA & (NN - 1)) * KKN + nl];
    int nB = nbi[(tB & (NN - 1)) * KKN + nl];
    uint4 fyA = ((const uint4*)(xhf + ((size_t)((tA >> 15) * NN + nA)) * OUT_DIM))[q];
    uint4 fyB = ((const uint4*)(xhf + ((size_t)((tB >> 15) * NN + nB)) * OUT_DIM))[q];
    uint2 paA, paB;
    if (q == 0) {
        float2 ip, op;
        ip = ((const float2*)igrid)[nA]; op = ((const float2*)ogrid)[tA & (NN - 1)];
        paA.x = cvt2u(ip.x, ip.y); paA.y = cvt2u(op.x, op.y);
        ip = ((const float2*)igrid)[nB]; op = ((const float2*)ogrid)[tB & (NN - 1)];
        paB.x = cvt2u(ip.x, ip.y); paB.y = cvt2u(op.x, op.y);
    }
    f16 xA0 = xhf[(size_t)tA * OUT_DIM + nl],      xA1 = xhf[(size_t)tA * OUT_DIM + 16 + nl];
    f16 xB0 = xhf[(size_t)tB * OUT_DIM + nl],      xB1 = xhf[(size_t)tB * OUT_DIM + 16 + nl];

    #pragma unroll 1
    for (int it = 0; it < TOT / (2 * NWAVES); ++it) {
        const float rA0 = (float)xA0, rA1 = (float)xA1, rB0 = (float)xB0, rB1 = (float)xB1;

        const int tA2 = (tA + 2 * NWAVES) & (TOT - 1);
        const int tB2 = tA2 + NWAVES;
        const int nA2 = nbi[(tA2 & (NN - 1)) * KKN + nl];
        const int nB2 = nbi[(tB2 & (NN - 1)) * KKN + nl];

        // ---- layer 1: A-operands straight from prefetched registers ----
        f16x8 aA0 = __builtin_bit_cast(f16x8, fyA);
        f16x8 aB0 = __builtin_bit_cast(f16x8, fyB);
        u32x4 uA1 = (u32x4){q == 0 ? paA.x : 0u, q == 0 ? paA.y : 0u, 0u, 0u};
        u32x4 uB1 = (u32x4){q == 0 ? paB.x : 0u, q == 0 ? paB.y : 0u, 0u, 0u};
        f16x8 aA1 = __builtin_bit_cast(f16x8, uA1);
        f16x8 aB1 = __builtin_bit_cast(f16x8, uB1);

        f32x4 cA[4], cB[4];
        #pragma unroll
        for (int nb = 0; nb < 4; nb++) {
            f16x8 W0 = WFRAG(nb);
            cA[nb] = __builtin_amdgcn_mfma_f32_16x16x32_f16(aA0, W0, zq, 0, 0, 0);
            cB[nb] = __builtin_amdgcn_mfma_f32_16x16x32_f16(aB0, W0, zq, 0, 0, 0);
        }
        #pragma unroll
        for (int nb = 0; nb < 4; nb++) {
            f16x8 W1 = WFRAG(4 + nb);
            cA[nb] = __builtin_amdgcn_mfma_f32_16x16x32_f16(aA1, W1, cA[nb], 0, 0, 0);
            cB[nb] = __builtin_amdgcn_mfma_f32_16x16x32_f16(aB1, W1, cB[nb], 0, 0, 0);
        }
        #pragma unroll
        for (int r = 0; r < 4; r++) {
            unsigned hA01 = gelu2bu(cA[0][r], cA[1][r], b1q0, gk);
            unsigned hA23 = gelu2bu(cA[2][r], cA[3][r], b1q1, gk);
            unsigned hB01 = gelu2bu(cB[0][r], cB[1][r], b1q0, gk);
            unsigned hB23 = gelu2bu(cB[2][r], cB[3][r], b1q1, gk);
            *(uint2*)&TA[(q * 4 + r) * WS + nl * 4] = (uint2){hA01, hA23};
            *(uint2*)&TB[(q * 4 + r) * WS + nl * 4] = (uint2){hB01, hB23};
        }

        // ---- issue next pair's gathers (overlap layers 2-3) ----
        uint4 fyA2 = ((const uint4*)(xhf + ((size_t)((tA2 >> 15) * NN + nA2)) * OUT_DIM))[q];
        uint4 fyB2 = ((const uint4*)(xhf + ((size_t)((tB2 >> 15) * NN + nB2)) * OUT_DIM))[q];
        uint2 paA2, paB2;
        if (q == 0) {
            float2 ip, op;
            ip = ((const float2*)igrid)[nA2]; op = ((const float2*)ogrid)[tA2 & (NN - 1)];
            paA2.x = cvt2u(ip.x, ip.y); paA2.y = cvt2u(op.x, op.y);
            ip = ((const float2*)igrid)[nB2]; op = ((const float2*)ogrid)[tB2 & (NN - 1)];
            paB2.x = cvt2u(ip.x, ip.y); paB2.y = cvt2u(op.x, op.y);
        }
        f16 xA0n = xhf[(size_t)tA2 * OUT_DIM + nl],  xA1n = xhf[(size_t)tA2 * OUT_DIM + 16 + nl];
        f16 xB0n = xhf[(size_t)tB2 * OUT_DIM + nl],  xB1n = xhf[(size_t)tB2 * OUT_DIM + 16 + nl];

        // ---- layer 2 ----
        f16x8 bA0 = *(const f16x8*)&TA[nl * WS + q * 8];
        f16x8 bA1 = *(const f16x8*)&TA[nl * WS + 32 + q * 8];
        f16x8 bB0 = *(const f16x8*)&TB[nl * WS + q * 8];
        f16x8 bB1 = *(const f16x8*)&TB[nl * WS + 32 + q * 8];
        #pragma unroll
        for (int nb = 0; nb < 4; nb++) {
            f16x8 W0 = WFRAG(8 + nb);
            cA[nb] = __builtin_amdgcn_mfma_f32_16x16x32_f16(bA0, W0, zq, 0, 0, 0);
            cB[nb] = __builtin_amdgcn_mfma_f32_16x16x32_f16(bB0, W0, zq, 0, 0, 0);
        }
        #pragma unroll
        for (int nb = 0; nb < 4; nb++) {
            f16x8 W1 = WFRAG(12 + nb);
            cA[nb] = __builtin_amdgcn_mfma_f32_16x16x32_f16(bA1, W1, cA[nb], 0, 0, 0);
            cB[nb] = __builtin_amdgcn_mfma_f32_16x16x32_f16(bB1, W1, cB[nb], 0, 0, 0);
        }
        #pragma unroll
        for (int r = 0; r < 4; r++) {
            unsigned hA01 = gelu2bu(cA[0][r], cA[1][r], b2q0, gk);
            unsigned hA23 = gelu2bu(cA[2][r], cA[3][r], b2q1, gk);
            unsigned hB01 = gelu2bu(cB[0][r], cB[1][r], b2q0, gk);
            unsigned hB23 = gelu2bu(cB[2][r], cB[3][r], b2q1, gk);
            *(uint2*)&TA[(q * 4 + r) * WS + nl * 4] = (uint2){hA01, hA23};
            *(uint2*)&TB[(q * 4 + r) * WS + nl * 4] = (uint2){hB01, hB23};
        }

        // ---- layer 3 (w3 pre-scaled by 1/16) ----
        bA0 = *(const f16x8*)&TA[nl * WS + q * 8];
        bA1 = *(const f16x8*)&TA[nl * WS + 32 + q * 8];
        bB0 = *(const f16x8*)&TB[nl * WS + q * 8];
        bB1 = *(const f16x8*)&TB[nl * WS + 32 + q * 8];
        f32x4 dA[2], dB[2];
        #pragma unroll
        for (int nb = 0; nb < 2; nb++) {
            f16x8 W0 = WFRAG(16 + nb);
            dA[nb] = __builtin_amdgcn_mfma_f32_16x16x32_f16(bA0, W0, zq, 0, 0, 0);
            dB[nb] = __builtin_amdgcn_mfma_f32_16x16x32_f16(bB0, W0, zq, 0, 0, 0);
        }
        #pragma unroll
        for (int nb = 0; nb < 2; nb++) {
            f16x8 W1 = WFRAG(18 + nb);
            dA[nb] = __builtin_amdgcn_mfma_f32_16x16x32_f16(bA1, W1, dA[nb], 0, 0, 0);
            dB[nb] = __builtin_amdgcn_mfma_f32_16x16x32_f16(bB1, W1, dB[nb], 0, 0, 0);
        }

        // ---- epilogues: edge-mean (pre-scaled) + bias + residual, LN over 32 ----
        {
            float s0 = dA[0][0] + dA[0][1] + dA[0][2] + dA[0][3];
            float s1 = dA[1][0] + dA[1][1] + dA[1][2] + dA[1][3];
            float u0 = dB[0][0] + dB[0][1] + dB[0][2] + dB[0][3];
            float u1 = dB[1][0] + dB[1][1] + dB[1][2] + dB[1][3];
            s0 += __shfl_xor(s0, 16, 64); s0 += __shfl_xor(s0, 32, 64);
            s1 += __shfl_xor(s1, 16, 64); s1 += __shfl_xor(s1, 32, 64);
            u0 += __shfl_xor(u0, 16, 64); u0 += __shfl_xor(u0, 32, 64);
            u1 += __shfl_xor(u1, 16, 64); u1 += __shfl_xor(u1, 32, 64);

            float oA0 = s0 + b3v[0] + rA0;
            float oA1 = s1 + b3v[1] + rA1;
            float oB0 = u0 + b3v[0] + rB0;
            float oB1 = u1 + b3v[1] + rB1;

            float mA = rowsum16(oA0 + oA1) * (1.0f / 32.0f);
            float mB = rowsum16(oB0 + oB1) * (1.0f / 32.0f);
            float dA0 = oA0 - mA, dA1 = oA1 - mA, dB0 = oB0 - mB, dB1 = oB1 - mB;
            float vA = rowsum16(dA0 * dA0 + dA1 * dA1) * (1.0f / 32.0f);
            float vB = rowsum16(dB0 * dB0 + dB1 * dB1) * (1.0f / 32.0f);
            float rsA = rsqrtf(vA + 1e-5f);
            float rsB = rsqrtf(vB + 1e-5f);

            if (q == 0) {
                float* oa = out + (size_t)tA * OUT_DIM;
                float* ob = out + (size_t)tB * OUT_DIM;
                oa[nl]      = fmaf(dA0 * rsA, g0, be0);
                oa[16 + nl] = fmaf(dA1 * rsA, g1, be1);
                ob[nl]      = fmaf(dB0 * rsB, g0, be0);
                ob[16 + nl] = fmaf(dB1 * rsB, g1, be1);
            }
        }

        // ---- rotate prefetch state ----
        tA = tA2; tB = tB2;
        fyA = fyA2; fyB = fyB2;
        paA = paA2; paB = paB2;
        xA0 = xA0n; xA1 = xA1n; xB0 = xB0n; xB1 = xB1n;
    }
    #undef WFRAG
}

extern "C" void kernel_launch(void* const* d_in, const int* in_sizes, int n_in,
                              void* d_out, int out_size, void* d_ws, size_t ws_size,
                              hipStream_t stream) {
    const float* inp   = (const float*)d_in[0];
    const float* igrid = (const float*)d_in[1];
    const float* ogrid = (const float*)d_in[2];
    const int*   nbi   = (const int*)d_in[3];
    const float* Wp1   = (const float*)d_in[4];
    const float* bp1   = (const float*)d_in[5];
    const float* Wp2   = (const float*)d_in[6];
    const float* bp2   = (const float*)d_in[7];
    const float* Wk1   = (const float*)d_in[8];
    const float* bk1   = (const float*)d_in[9];
    const float* Wk2   = (const float*)d_in[10];
    const float* bk2   = (const float*)d_in[11];
    const float* Wk3   = (const float*)d_in[12];
    const float* bk3   = (const float*)d_in[13];
    const float* gma   = (const float*)d_in[14];
    const float* bta   = (const float*)d_in[15];
    float* out = (float*)d_out;
    f16* xhf = (f16*)d_ws;   // B*N*32 f16 = 8 MB

    point_mlp_kernel<<<1024, 256, 0, stream>>>(inp, Wp1, bp1, Wp2, bp2, xhf);
    gnn_edge_kernel<<<1024, 256, 0, stream>>>(xhf, igrid, ogrid, nbi,
                                              Wk1, bk1, Wk2, bk2, Wk3, bk3,
                                              gma, bta, out);
}